// Round 8
// baseline (635.015 us; speedup 1.0000x reference)
//
#include <hip/hip_runtime.h>
#include <hip/hip_bf16.h>
#include <stdint.h>

#define AS1 __attribute__((address_space(1)))
#define AS3 __attribute__((address_space(3)))

typedef short bf16x8 __attribute__((ext_vector_type(8)));
typedef float f32x4 __attribute__((ext_vector_type(4)));

static constexpr int LSEQ   = 1024;
static constexpr int DINNER = 2048;
static constexpr int CCH    = 2176;   // conv channels
static constexpr int DPROJ  = 4256;
static constexpr int DPROJP = 4352;   // padded to 34*128
static constexpr int CHUNK  = 64;     // scan chunk length
static constexpr int NCHUNK = LSEQ / CHUNK;   // 16

__device__ __forceinline__ float bf2f(ushort u) {
  union { uint32_t i; float f; } v; v.i = ((uint32_t)u) << 16; return v.f;
}
__device__ __forceinline__ ushort f2bf(float f) {
  union { float f; uint32_t i; } v; v.f = f;
  uint32_t r = v.i + 0x7fffu + ((v.i >> 16) & 1u);   // RNE
  return (ushort)(r >> 16);
}
__device__ __forceinline__ float siluf(float v) { return v / (1.f + __expf(-v)); }

// ---------------- elementwise f32 -> bf16 ----------------
__global__ void convert_f32_bf16(const float* __restrict__ src, ushort* __restrict__ dst, int n) {
  int i = (blockIdx.x * blockDim.x + threadIdx.x) * 4;
  if (i < n) {
    float4 v = *(const float4*)(src + i);
    ushort4 o; o.x = f2bf(v.x); o.y = f2bf(v.y); o.z = f2bf(v.z); o.w = f2bf(v.w);
    *(ushort4*)(dst + i) = o;
  }
}

// ---------------- transpose f32 [R][C] -> bf16 [Cpad][R], zero-fill pad rows ----
__global__ void transpose_f32_bf16(const float* __restrict__ src, ushort* __restrict__ dst,
                                   int R, int C) {
  __shared__ float tile[32][33];
  int c0 = blockIdx.x * 32, r0 = blockIdx.y * 32;
  int tx = threadIdx.x, ty = threadIdx.y;
  #pragma unroll
  for (int j = 0; j < 4; ++j) {
    int c = c0 + tx, r = r0 + ty + j * 8;
    tile[ty + j * 8][tx] = (c < C) ? src[(size_t)r * C + c] : 0.f;
  }
  __syncthreads();
  #pragma unroll
  for (int j = 0; j < 4; ++j) {
    int cc = c0 + ty + j * 8, rr = r0 + tx;
    dst[(size_t)cc * R + rr] = f2bf(tile[tx][ty + j * 8]);
  }
}

// ---------------- bf16 MFMA GEMM: C[M][N] = A[M][K] * Bt[N][K]^T (+bias) -------
// 128x128 tile, BK=32, 4 waves (2x2), double-buffered LDS via global_load_lds.
// blockIdx.z selects a batch slice via element strides sA/sB/sC (dir fusion).
template<int OUT_BF16, int ADD_BIAS>
__global__ __launch_bounds__(256) void gemm_bt(
    const ushort* __restrict__ A, const ushort* __restrict__ Bt,
    void* __restrict__ Cp, const float* __restrict__ bias,
    int M, int N, int K, int ldc,
    size_t sA, size_t sB, size_t sC)
{
  __shared__ char lds[32768];   // 2 bufs x (A 8KB + B 8KB)
  const int tid  = threadIdx.x;
  const int lane = tid & 63;
  const int wid  = tid >> 6;
  const int wm = wid >> 1, wn = wid & 1;
  const int m0 = blockIdx.y * 128, n0 = blockIdx.x * 128;
  const size_t zo = blockIdx.z;
  A  += zo * sA;
  Bt += zo * sB;

  f32x4 acc[4][4];
  {
    f32x4 z = {0.f, 0.f, 0.f, 0.f};
    #pragma unroll
    for (int i = 0; i < 4; ++i)
      #pragma unroll
      for (int j = 0; j < 4; ++j) acc[i][j] = z;
  }

  const int rr = tid >> 2;            // staging row within 64-row half
  const int ce = (tid & 3) * 8;       // staging k-element offset

  auto stage = [&](int buf, int kt) {
    const int k0 = kt * 32;
    char* base = lds + buf * 16384;
    #pragma unroll
    for (int q = 0; q < 2; ++q) {
      const ushort* ga = A + (size_t)(m0 + q * 64 + rr) * K + (k0 + ce);
      __builtin_amdgcn_global_load_lds((AS1 void*)ga,
          (AS3 void*)(base + q * 4096 + wid * 1024), 16, 0, 0);
    }
    #pragma unroll
    for (int q = 0; q < 2; ++q) {
      const ushort* gb = Bt + (size_t)(n0 + q * 64 + rr) * K + (k0 + ce);
      __builtin_amdgcn_global_load_lds((AS1 void*)gb,
          (AS3 void*)(base + 8192 + q * 4096 + wid * 1024), 16, 0, 0);
    }
  };

  auto compute = [&](int buf) {
    const char* base = lds + buf * 16384;
    const int ra = lane & 15;
    const int kb = (lane >> 4) * 16;
    bf16x8 af[4], bfr[4];
    #pragma unroll
    for (int mt = 0; mt < 4; ++mt)
      af[mt] = *(const bf16x8*)(base + (wm * 64 + mt * 16 + ra) * 64 + kb);
    #pragma unroll
    for (int nt = 0; nt < 4; ++nt)
      bfr[nt] = *(const bf16x8*)(base + 8192 + (wn * 64 + nt * 16 + ra) * 64 + kb);
    #pragma unroll
    for (int mt = 0; mt < 4; ++mt)
      #pragma unroll
      for (int nt = 0; nt < 4; ++nt)
        acc[mt][nt] = __builtin_amdgcn_mfma_f32_16x16x32_bf16(af[mt], bfr[nt], acc[mt][nt], 0, 0, 0);
  };

  const int NT = K >> 5;
  stage(0, 0);
  __syncthreads();
  for (int kt = 0; kt < NT; ++kt) {
    if (kt + 1 < NT) stage((kt + 1) & 1, kt + 1);
    compute(kt & 1);
    __syncthreads();   // drains vmcnt(0): next buffer staged, this buffer's reads done
  }

  const int rbase = m0 + wm * 64 + (lane >> 4) * 4;
  const int cbase = n0 + wn * 64 + (lane & 15);
  #pragma unroll
  for (int mt = 0; mt < 4; ++mt) {
    #pragma unroll
    for (int nt = 0; nt < 4; ++nt) {
      const int col = cbase + nt * 16;
      float bv = ADD_BIAS ? bias[col] : 0.f;
      #pragma unroll
      for (int e = 0; e < 4; ++e) {
        const int row = rbase + mt * 16 + e;
        float v = acc[mt][nt][e] + bv;
        if (OUT_BF16) ((ushort*)Cp)[zo * sC + (size_t)row * ldc + col] = f2bf(v);
        else          ((float*) Cp)[zo * sC + (size_t)row * ldc + col] = v;
      }
    }
  }
}

// ---------------- depthwise conv (causal fwd / anti-causal bwd) + silu + dt/dA --
__global__ __launch_bounds__(256) void conv_prep(
    const ushort* __restrict__ zx,      // [2][2048][4352] bf16
    const float* __restrict__ fconvw, const float* __restrict__ fconvb,
    const float* __restrict__ bconvw, const float* __restrict__ bconvb,
    const float* __restrict__ fdtb, const float* __restrict__ fAlog,
    const float* __restrict__ bdtb, const float* __restrict__ bAlog,
    ushort* __restrict__ xs,            // [2][2048][2048] bf16
    float* __restrict__ BC,             // [2][2048][128]  (B then C)
    float* __restrict__ dtA)            // [2][2048][64]   (dt[32] then dA[32])
{
  const int bidx = blockIdx.x;          // dir*2048 + b*1024 + l
  const int dir  = bidx >> 11;
  const int l    = bidx & 1023;
  const int tid  = threadIdx.x;
  const float* convw = dir ? bconvw : fconvw;
  const float* convb = dir ? bconvb : fconvb;

  for (int c = tid; c < CCH; c += 256) {
    float acc = convb[c];
    if (dir == 0) {
      #pragma unroll
      for (int k = 0; k < 4; ++k) {
        int ls = l - 3 + k;
        if (ls >= 0)
          acc += bf2f(zx[(size_t)(bidx - 3 + k) * DPROJP + DINNER + c]) * convw[k * CCH + c];
      }
    } else {
      #pragma unroll
      for (int j = 0; j < 4; ++j) {
        int ls = l + j;
        if (ls < LSEQ)
          acc += bf2f(zx[(size_t)(bidx + j) * DPROJP + DINNER + c]) * convw[(3 - j) * CCH + c];
      }
    }
    float v = siluf(acc);
    if (c < DINNER) xs[(size_t)bidx * 2048 + c] = f2bf(v);
    else            BC[(size_t)bidx * 128 + (c - DINNER)] = v;
  }
  if (tid < 32) {
    const int h = tid;
    float dtb  = dir ? bdtb[h]  : fdtb[h];
    float Alog = dir ? bAlog[h] : fAlog[h];
    float draw = bf2f(zx[(size_t)bidx * DPROJP + 4224 + h]) + dtb;
    float dt = (draw > 15.f) ? draw : log1pf(__expf(draw));
    float dA = __expf(dt * -__expf(Alog));
    dtA[(size_t)bidx * 64 + h]      = dt;
    dtA[(size_t)bidx * 64 + 32 + h] = dA;
  }
}

// ---------------- chunked selective scan, wave-per-(group,chunk,n-half) -----
// group g = (dir*2+b)*32+h (128 groups); chunk ch (16); half = n-half (2).
// 4 waves per 256-thr block (workgroup-slot fix); each wave owns one
// (g,ch,half); lane = p. State hs[n'=0..31] in VGPRs. B/C/dt/dA wave-uniform
// -> scalar loads feeding v_fmac v,s,v. No cross-lane ops. Each half writes
// its y-partial to its own bf16 buffer (summed in norm).
__global__ __launch_bounds__(256, 8) void scan_local2(
    const ushort* __restrict__ xs, const float* __restrict__ BC,
    const float* __restrict__ dtA, const float* __restrict__ fD,
    const float* __restrict__ bD,
    ushort* __restrict__ Y0, ushort* __restrict__ Y1,   // bf16 y-partials
    ushort* __restrict__ hendb,         // [128*NCHUNK][p=64][n=64] bf16
    float* __restrict__ Afull)          // [128][NCHUNK]
{
  const int bid  = blockIdx.x * 4 + (threadIdx.x >> 6);   // ((g*NCHUNK)+ch)*2+half
  const int half = bid & 1;
  const int ch   = (bid >> 1) & (NCHUNK - 1);
  const int g    = bid >> 5;
  const int h    = g & 31;
  const int b    = (g >> 5) & 1;
  const int dir  = g >> 6;
  const int p    = threadIdx.x & 63;    // 0..63
  const int n0   = half * 32;
  const float Dh = (dir ? bD : fD)[h];
  const int rowbase = dir * 2048 + b * 1024;
  const int t0 = ch * CHUNK;
  ushort* __restrict__ yh = half ? Y1 : Y0;

  float hs[32];
  #pragma unroll
  for (int i = 0; i < 32; ++i) hs[i] = 0.f;
  float P = 1.f;

  // prefetch first x
  int l0 = dir ? (LSEQ - 1 - t0) : t0;
  ushort xr = xs[(size_t)(rowbase + l0) * 2048 + h * 64 + p];

  for (int step = 0; step < CHUNK; ++step) {
    const int tau = t0 + step;
    const int l   = dir ? (LSEQ - 1 - tau) : tau;
    const int row = rowbase + l;
    // prefetch next step's x
    ushort xnext = 0;
    if (step + 1 < CHUNK) {
      const int ln = dir ? (l - 1) : (l + 1);
      xnext = xs[(size_t)(rowbase + ln) * 2048 + h * 64 + p];
    }
    const float dt = dtA[(size_t)row * 64 + h];        // uniform -> s_load
    const float dA = dtA[(size_t)row * 64 + 32 + h];   // uniform -> s_load
    const float* __restrict__ Brow = BC + (size_t)row * 128 + n0;        // uniform
    const float* __restrict__ Crow = BC + (size_t)row * 128 + 64 + n0;   // uniform
    const float xv = bf2f(xr);
    const float a  = dt * xv;
    float yp0 = 0.f, yp1 = 0.f, yp2 = 0.f, yp3 = 0.f;
    #pragma unroll
    for (int n = 0; n < 32; n += 4) {
      hs[n+0] = dA * hs[n+0] + a * Brow[n+0]; yp0 += Crow[n+0] * hs[n+0];
      hs[n+1] = dA * hs[n+1] + a * Brow[n+1]; yp1 += Crow[n+1] * hs[n+1];
      hs[n+2] = dA * hs[n+2] + a * Brow[n+2]; yp2 += Crow[n+2] * hs[n+2];
      hs[n+3] = dA * hs[n+3] + a * Brow[n+3]; yp3 += Crow[n+3] * hs[n+3];
    }
    P *= dA;
    float yp = (yp0 + yp1) + (yp2 + yp3);
    if (half == 0) yp += Dh * xv;       // D-skip term once
    yh[(size_t)row * 2048 + h * 64 + p] = f2bf(yp);
    xr = xnext;
  }

  // write this half's h_end columns (32 contiguous bf16 per lane)
  ushort* dst = hendb + (size_t)(bid >> 1) * 4096 + p * 64 + n0;
  #pragma unroll
  for (int n = 0; n < 32; n += 8) {
    ushort o8[8];
    #pragma unroll
    for (int j = 0; j < 8; ++j) o8[j] = f2bf(hs[n + j]);
    *(int4*)(dst + n) = *(int4*)o8;
  }
  if (half == 0 && p == 0) Afull[g * NCHUNK + ch] = P;
}

// Pass 2: carry h across chunks (elementwise over 4096 state elems, bf16 io).
// Overwrites hendb[g][ch] with h_in(ch) (carry BEFORE chunk ch).
__global__ __launch_bounds__(512) void scan_combine2(
    ushort* __restrict__ hendb, const float* __restrict__ Afull)
{
  const int g   = blockIdx.x;           // 128 groups
  const int off = threadIdx.x * 8;      // 512*8 = 4096 elems
  float ca[8];
  #pragma unroll
  for (int i = 0; i < 8; ++i) ca[i] = 0.f;
  for (int ch = 0; ch < NCHUNK; ++ch) {
    ushort* hb = hendb + (size_t)(g * NCHUNK + ch) * 4096 + off;
    ushort e8[8];
    *(int4*)e8 = *(const int4*)hb;
    ushort o8[8];
    #pragma unroll
    for (int i = 0; i < 8; ++i) o8[i] = f2bf(ca[i]);
    *(int4*)hb = *(int4*)o8;            // h_in for this chunk
    const float A = Afull[g * NCHUNK + ch];
    #pragma unroll
    for (int i = 0; i < 8; ++i) ca[i] = A * ca[i] + bf2f(e8[i]);
  }
}

// Pass 3: y[t] += P_t * (C_t . h_in(chunk)), split by n-half like pass 1.
// 4 waves per block; each half-wave RMWs its own bf16 Y-half (exclusive rows).
__global__ __launch_bounds__(256, 8) void scan_corr2(
    const float* __restrict__ BC, const ushort* __restrict__ hinb,
    const float* __restrict__ dtA,
    ushort* __restrict__ Y0, ushort* __restrict__ Y1)
{
  const int bid  = blockIdx.x * 4 + (threadIdx.x >> 6);   // ((g*NCHUNK)+ch)*2+half
  const int half = bid & 1;
  const int ch   = (bid >> 1) & (NCHUNK - 1);
  if (ch == 0) return;                  // h_in(0) == 0
  const int g    = bid >> 5;
  const int h    = g & 31;
  const int b    = (g >> 5) & 1;
  const int dir  = g >> 6;
  const int p    = threadIdx.x & 63;
  const int n0   = half * 32;
  const int rowbase = dir * 2048 + b * 1024;
  const int t0 = ch * CHUNK;
  ushort* __restrict__ yh = half ? Y1 : Y0;

  float hin[32];
  {
    const ushort* hb = hinb + (size_t)(bid >> 1) * 4096 + p * 64 + n0;
    #pragma unroll
    for (int n = 0; n < 32; n += 8) {
      ushort e8[8];
      *(int4*)e8 = *(const int4*)(hb + n);
      #pragma unroll
      for (int j = 0; j < 8; ++j) hin[n + j] = bf2f(e8[j]);
    }
  }

  float P = 1.f;
  for (int step = 0; step < CHUNK; ++step) {
    const int tau = t0 + step;
    const int l   = dir ? (LSEQ - 1 - tau) : tau;
    const int row = rowbase + l;
    const float dA = dtA[(size_t)row * 64 + 32 + h];   // uniform
    P *= dA;
    const float* __restrict__ Crow = BC + (size_t)row * 128 + 64 + n0;   // uniform
    float s0 = 0.f, s1 = 0.f, s2 = 0.f, s3 = 0.f;
    #pragma unroll
    for (int n = 0; n < 32; n += 4) {
      s0 += Crow[n+0] * hin[n+0];
      s1 += Crow[n+1] * hin[n+1];
      s2 += Crow[n+2] * hin[n+2];
      s3 += Crow[n+3] * hin[n+3];
    }
    const size_t yi = (size_t)row * 2048 + h * 64 + p;
    yh[yi] = f2bf(bf2f(yh[yi]) + ((s0 + s1) + (s2 + s3)) * P);
  }
}

// ---------------- gated RMSNorm: yn = ((Y0+Y1)*silu(z)) * rsqrt(mean sq) * normw
__global__ __launch_bounds__(256) void norm_kernel(
    const ushort* __restrict__ Y0, const ushort* __restrict__ Y1,
    const ushort* __restrict__ zx,
    const float* __restrict__ fnormw, const float* __restrict__ bnormw,
    ushort* __restrict__ yn)
{
  const int bidx = blockIdx.x;          // dir*2048 + row
  const int dir  = bidx >> 11;
  const int tid  = threadIdx.x;
  const float* nw = dir ? bnormw : fnormw;
  const ushort* zrow = zx + (size_t)bidx * DPROJP;
  const int c = tid * 8;
  const size_t yoff = (size_t)bidx * 2048 + c;

  ushort a8[8], b8[8], z8[8];
  *(int4*)a8 = *(const int4*)(Y0 + yoff);
  *(int4*)b8 = *(const int4*)(Y1 + yoff);
  *(int4*)z8 = *(const int4*)(zrow + c);
  float g[8];
  #pragma unroll
  for (int j = 0; j < 8; ++j)
    g[j] = (bf2f(a8[j]) + bf2f(b8[j])) * siluf(bf2f(z8[j]));
  float ss = 0.f;
  #pragma unroll
  for (int j = 0; j < 8; ++j) ss += g[j] * g[j];
  #pragma unroll
  for (int off = 32; off > 0; off >>= 1) ss += __shfl_xor(ss, off);
  __shared__ float red[4];
  const int wid = tid >> 6, lane = tid & 63;
  if (lane == 0) red[wid] = ss;
  __syncthreads();
  const float tot = red[0] + red[1] + red[2] + red[3];
  const float scale = rsqrtf(tot * (1.f / 2048.f) + 1e-5f);
  ushort o8[8];
  #pragma unroll
  for (int j = 0; j < 8; ++j) o8[j] = f2bf(g[j] * scale * nw[c + j]);
  *(int4*)(yn + (size_t)bidx * 2048 + c) = *(int4*)o8;
}

// -------------------------------------------------------------------------------
extern "C" void kernel_launch(void* const* d_in, const int* in_sizes, int n_in,
                              void* d_out, int out_size, void* d_ws, size_t ws_size,
                              hipStream_t stream)
{
  const float* x      = (const float*)d_in[0];
  const float* fWin   = (const float*)d_in[1];
  const float* fconvw = (const float*)d_in[2];
  const float* fconvb = (const float*)d_in[3];
  const float* fdtb   = (const float*)d_in[4];
  const float* fAlog  = (const float*)d_in[5];
  const float* fD     = (const float*)d_in[6];
  const float* fnormw = (const float*)d_in[7];
  const float* fWout  = (const float*)d_in[8];
  const float* bWin   = (const float*)d_in[9];
  const float* bconvw = (const float*)d_in[10];
  const float* bconvb = (const float*)d_in[11];
  const float* bdtb   = (const float*)d_in[12];
  const float* bAlog  = (const float*)d_in[13];
  const float* bD     = (const float*)d_in[14];
  const float* bnormw = (const float*)d_in[15];
  const float* bWout  = (const float*)d_in[16];
  const float* Wo     = (const float*)d_in[17];
  const float* bo     = (const float*)d_in[18];

  char* ws = (char*)d_ws;
  ushort* XB    = (ushort*)(ws);               // x bf16               [2048][1024]
  ushort* WINT  = (ushort*)(ws + 4194304);     // Win^T bf16 (padded)  [2][4352][1024]
  ushort* WOUTT = (ushort*)(ws + 22020096);    // Wout^T bf16          [2][1024][2048]
  ushort* WOT   = (ushort*)(ws + 30408704);    // Wo^T bf16            [1024][2048]
  ushort* ZX    = (ushort*)(ws + 34603008);    // zxbcdt bf16          [2][2048][4352]
  ushort* XS    = (ushort*)(ws + 70254592);    // conv'd x bf16        [2][2048][2048]
  float*  BCB   = (float*) (ws + 87031808);    // B,C f32              [2][2048][128]
  float*  DTA   = (float*) (ws + 89128960);    // dt,dA f32            [2][2048][64]
  ushort* Y0B   = (ushort*)(ws + 90177536);    // y partial n<32 bf16  [2][2048][2048]
  ushort* Y1B   = (ushort*)(ws + 106954752);   // y partial n>=32 bf16 [2][2048][2048]
  ushort* YN    = (ushort*)(ws + 123731968);   // normed bf16          [2][2048][2048]
  ushort* OUT2  = (ushort*)(ws + 140509184);   // concat(fwd,rev) bf16 [2048][2048]
  // HENDB/AFULL alias the WINT region (17.83 MB): WINT is dead after the
  // in-projection GEMM completes; scan_local2 runs strictly after it.
  // Total ws stays at the proven 148,897,792 bytes.
  ushort* HENDB = (ushort*)(ws + 4194304);     // h_end->h_in bf16 [2048][64][64] (16.78 MB)
  float*  AFULL = (float*) (ws + 20971520);    // chunk decay totals [128][16] (8 KB)

  // --- convert / transpose weights & activations to bf16 (B^T layouts) ---
  convert_f32_bf16<<<2048, 256, 0, stream>>>(x, XB, 2048 * 1024);
  transpose_f32_bf16<<<dim3(136, 32), dim3(32, 8), 0, stream>>>(fWin, WINT, 1024, 4256);
  transpose_f32_bf16<<<dim3(136, 32), dim3(32, 8), 0, stream>>>(bWin, WINT + (size_t)4352 * 1024, 1024, 4256);
  transpose_f32_bf16<<<dim3(32, 64),  dim3(32, 8), 0, stream>>>(fWout, WOUTT, 2048, 1024);
  transpose_f32_bf16<<<dim3(32, 64),  dim3(32, 8), 0, stream>>>(bWout, WOUTT + (size_t)1024 * 2048, 2048, 1024);
  transpose_f32_bf16<<<dim3(32, 64),  dim3(32, 8), 0, stream>>>(Wo, WOT, 2048, 1024);

  // --- in-projection, both directions fused via gridDim.z ---
  gemm_bt<1, 0><<<dim3(34, 16, 2), 256, 0, stream>>>(
      XB, WINT, (void*)ZX, nullptr, 2048, 4352, 1024, 4352,
      0, (size_t)4352 * 1024, (size_t)2048 * 4352);

  // --- conv (causal fwd / anti-causal bwd) + silu + dt/dA ---
  conv_prep<<<4096, 256, 0, stream>>>(ZX, fconvw, fconvb, bconvw, bconvb,
                                      fdtb, fAlog, bdtb, bAlog, XS, BCB, DTA);

  // --- chunked selective scan, n-split, 4 waves/block ---
  scan_local2<<<128 * NCHUNK * 2 / 4, 256, 0, stream>>>(XS, BCB, DTA, fD, bD,
                                                        Y0B, Y1B, HENDB, AFULL);
  scan_combine2<<<128, 512, 0, stream>>>(HENDB, AFULL);
  scan_corr2<<<128 * NCHUNK * 2 / 4, 256, 0, stream>>>(BCB, HENDB, DTA, Y0B, Y1B);

  // --- gated RMSNorm (sums the two y partials) ---
  norm_kernel<<<4096, 256, 0, stream>>>(Y0B, Y1B, ZX, fnormw, bnormw, YN);

  // --- out-projections (both dirs fused) into concat buffer, then final Wo ---
  gemm_bt<1, 0><<<dim3(8, 16, 2), 256, 0, stream>>>(
      YN, WOUTT, (void*)OUT2, nullptr, 2048, 1024, 2048, 2048,
      (size_t)2048 * 2048, (size_t)1024 * 2048, (size_t)1024);
  gemm_bt<0, 1><<<dim3(8, 16), 256, 0, stream>>>(
      OUT2, WOT, d_out, bo, 2048, 1024, 2048, 1024, 0, 0, 0);
}

// Round 9
// 460.083 us; speedup vs baseline: 1.3802x; 1.3802x over previous
//
#include <hip/hip_runtime.h>
#include <hip/hip_bf16.h>
#include <stdint.h>

#define AS1 __attribute__((address_space(1)))
#define AS3 __attribute__((address_space(3)))

typedef short bf16x8 __attribute__((ext_vector_type(8)));
typedef float f32x4 __attribute__((ext_vector_type(4)));

static constexpr int LSEQ   = 1024;
static constexpr int DINNER = 2048;
static constexpr int CCH    = 2176;   // conv channels
static constexpr int DPROJ  = 4256;
static constexpr int DPROJP = 4352;   // padded to 34*128
static constexpr int CHUNK  = 64;     // scan chunk length
static constexpr int NCHUNK = LSEQ / CHUNK;   // 16

__device__ __forceinline__ float bf2f(ushort u) {
  union { uint32_t i; float f; } v; v.i = ((uint32_t)u) << 16; return v.f;
}
__device__ __forceinline__ ushort f2bf(float f) {
  union { float f; uint32_t i; } v; v.f = f;
  uint32_t r = v.i + 0x7fffu + ((v.i >> 16) & 1u);   // RNE
  return (ushort)(r >> 16);
}
__device__ __forceinline__ float siluf(float v) { return v / (1.f + __expf(-v)); }

// ---------------- elementwise f32 -> bf16 ----------------
__global__ void convert_f32_bf16(const float* __restrict__ src, ushort* __restrict__ dst, int n) {
  int i = (blockIdx.x * blockDim.x + threadIdx.x) * 4;
  if (i < n) {
    float4 v = *(const float4*)(src + i);
    ushort4 o; o.x = f2bf(v.x); o.y = f2bf(v.y); o.z = f2bf(v.z); o.w = f2bf(v.w);
    *(ushort4*)(dst + i) = o;
  }
}

// ---------------- transpose f32 [R][C] -> bf16 [Cpad][R], zero-fill pad rows ----
__global__ void transpose_f32_bf16(const float* __restrict__ src, ushort* __restrict__ dst,
                                   int R, int C) {
  __shared__ float tile[32][33];
  int c0 = blockIdx.x * 32, r0 = blockIdx.y * 32;
  int tx = threadIdx.x, ty = threadIdx.y;
  #pragma unroll
  for (int j = 0; j < 4; ++j) {
    int c = c0 + tx, r = r0 + ty + j * 8;
    tile[ty + j * 8][tx] = (c < C) ? src[(size_t)r * C + c] : 0.f;
  }
  __syncthreads();
  #pragma unroll
  for (int j = 0; j < 4; ++j) {
    int cc = c0 + ty + j * 8, rr = r0 + tx;
    dst[(size_t)cc * R + rr] = f2bf(tile[tx][ty + j * 8]);
  }
}

// ---------------- bf16 MFMA GEMM: C[M][N] = A[M][K] * Bt[N][K]^T (+bias) -------
// 128x128 tile, BK=32, 4 waves (2x2), double-buffered LDS via global_load_lds.
// blockIdx.z selects a batch slice via element strides sA/sB/sC (dir fusion).
template<int OUT_BF16, int ADD_BIAS>
__global__ __launch_bounds__(256) void gemm_bt(
    const ushort* __restrict__ A, const ushort* __restrict__ Bt,
    void* __restrict__ Cp, const float* __restrict__ bias,
    int M, int N, int K, int ldc,
    size_t sA, size_t sB, size_t sC)
{
  __shared__ char lds[32768];   // 2 bufs x (A 8KB + B 8KB)
  const int tid  = threadIdx.x;
  const int lane = tid & 63;
  const int wid  = tid >> 6;
  const int wm = wid >> 1, wn = wid & 1;
  const int m0 = blockIdx.y * 128, n0 = blockIdx.x * 128;
  const size_t zo = blockIdx.z;
  A  += zo * sA;
  Bt += zo * sB;

  f32x4 acc[4][4];
  {
    f32x4 z = {0.f, 0.f, 0.f, 0.f};
    #pragma unroll
    for (int i = 0; i < 4; ++i)
      #pragma unroll
      for (int j = 0; j < 4; ++j) acc[i][j] = z;
  }

  const int rr = tid >> 2;            // staging row within 64-row half
  const int ce = (tid & 3) * 8;       // staging k-element offset

  auto stage = [&](int buf, int kt) {
    const int k0 = kt * 32;
    char* base = lds + buf * 16384;
    #pragma unroll
    for (int q = 0; q < 2; ++q) {
      const ushort* ga = A + (size_t)(m0 + q * 64 + rr) * K + (k0 + ce);
      __builtin_amdgcn_global_load_lds((AS1 void*)ga,
          (AS3 void*)(base + q * 4096 + wid * 1024), 16, 0, 0);
    }
    #pragma unroll
    for (int q = 0; q < 2; ++q) {
      const ushort* gb = Bt + (size_t)(n0 + q * 64 + rr) * K + (k0 + ce);
      __builtin_amdgcn_global_load_lds((AS1 void*)gb,
          (AS3 void*)(base + 8192 + q * 4096 + wid * 1024), 16, 0, 0);
    }
  };

  auto compute = [&](int buf) {
    const char* base = lds + buf * 16384;
    const int ra = lane & 15;
    const int kb = (lane >> 4) * 16;
    bf16x8 af[4], bfr[4];
    #pragma unroll
    for (int mt = 0; mt < 4; ++mt)
      af[mt] = *(const bf16x8*)(base + (wm * 64 + mt * 16 + ra) * 64 + kb);
    #pragma unroll
    for (int nt = 0; nt < 4; ++nt)
      bfr[nt] = *(const bf16x8*)(base + 8192 + (wn * 64 + nt * 16 + ra) * 64 + kb);
    #pragma unroll
    for (int mt = 0; mt < 4; ++mt)
      #pragma unroll
      for (int nt = 0; nt < 4; ++nt)
        acc[mt][nt] = __builtin_amdgcn_mfma_f32_16x16x32_bf16(af[mt], bfr[nt], acc[mt][nt], 0, 0, 0);
  };

  const int NT = K >> 5;
  stage(0, 0);
  __syncthreads();
  for (int kt = 0; kt < NT; ++kt) {
    if (kt + 1 < NT) stage((kt + 1) & 1, kt + 1);
    compute(kt & 1);
    __syncthreads();   // drains vmcnt(0): next buffer staged, this buffer's reads done
  }

  const int rbase = m0 + wm * 64 + (lane >> 4) * 4;
  const int cbase = n0 + wn * 64 + (lane & 15);
  #pragma unroll
  for (int mt = 0; mt < 4; ++mt) {
    #pragma unroll
    for (int nt = 0; nt < 4; ++nt) {
      const int col = cbase + nt * 16;
      float bv = ADD_BIAS ? bias[col] : 0.f;
      #pragma unroll
      for (int e = 0; e < 4; ++e) {
        const int row = rbase + mt * 16 + e;
        float v = acc[mt][nt][e] + bv;
        if (OUT_BF16) ((ushort*)Cp)[zo * sC + (size_t)row * ldc + col] = f2bf(v);
        else          ((float*) Cp)[zo * sC + (size_t)row * ldc + col] = v;
      }
    }
  }
}

// ---------------- depthwise conv (causal fwd / anti-causal bwd) + silu + dt/dA --
__global__ __launch_bounds__(256) void conv_prep(
    const ushort* __restrict__ zx,      // [2][2048][4352] bf16
    const float* __restrict__ fconvw, const float* __restrict__ fconvb,
    const float* __restrict__ bconvw, const float* __restrict__ bconvb,
    const float* __restrict__ fdtb, const float* __restrict__ fAlog,
    const float* __restrict__ bdtb, const float* __restrict__ bAlog,
    ushort* __restrict__ xs,            // [2][2048][2048] bf16
    float* __restrict__ BC,             // [2][2048][128]  (B then C)
    float* __restrict__ dtA)            // [2][2048][64]   (dt[32] then dA[32])
{
  const int bidx = blockIdx.x;          // dir*2048 + b*1024 + l
  const int dir  = bidx >> 11;
  const int l    = bidx & 1023;
  const int tid  = threadIdx.x;
  const float* convw = dir ? bconvw : fconvw;
  const float* convb = dir ? bconvb : fconvb;

  for (int c = tid; c < CCH; c += 256) {
    float acc = convb[c];
    if (dir == 0) {
      #pragma unroll
      for (int k = 0; k < 4; ++k) {
        int ls = l - 3 + k;
        if (ls >= 0)
          acc += bf2f(zx[(size_t)(bidx - 3 + k) * DPROJP + DINNER + c]) * convw[k * CCH + c];
      }
    } else {
      #pragma unroll
      for (int j = 0; j < 4; ++j) {
        int ls = l + j;
        if (ls < LSEQ)
          acc += bf2f(zx[(size_t)(bidx + j) * DPROJP + DINNER + c]) * convw[(3 - j) * CCH + c];
      }
    }
    float v = siluf(acc);
    if (c < DINNER) xs[(size_t)bidx * 2048 + c] = f2bf(v);
    else            BC[(size_t)bidx * 128 + (c - DINNER)] = v;
  }
  if (tid < 32) {
    const int h = tid;
    float dtb  = dir ? bdtb[h]  : fdtb[h];
    float Alog = dir ? bAlog[h] : fAlog[h];
    float draw = bf2f(zx[(size_t)bidx * DPROJP + 4224 + h]) + dtb;
    float dt = (draw > 15.f) ? draw : log1pf(__expf(draw));
    float dA = __expf(dt * -__expf(Alog));
    dtA[(size_t)bidx * 64 + h]      = dt;
    dtA[(size_t)bidx * 64 + 32 + h] = dA;
  }
}

// ---------------- chunked selective scan, wave-per-(group,chunk,n-half) -----
// group g = (dir*2+b)*32+h (128 groups); chunk ch (16); half = n-half (2).
// 4 waves per 256-thr block; wave id forced into SGPR via readfirstlane so
// all B/C/dt/dA addresses stay compiler-provably wave-uniform -> s_loads.
// State hs[n'=0..31] in VGPRs; lane = p. No cross-lane ops.
__global__ __launch_bounds__(256, 8) void scan_local2(
    const ushort* __restrict__ xs, const float* __restrict__ BC,
    const float* __restrict__ dtA, const float* __restrict__ fD,
    const float* __restrict__ bD,
    ushort* __restrict__ Y0, ushort* __restrict__ Y1,   // bf16 y-partials
    ushort* __restrict__ hendb,         // [128*NCHUNK][p=64][n=64] bf16
    float* __restrict__ Afull)          // [128][NCHUNK]
{
  const int wv   = __builtin_amdgcn_readfirstlane(threadIdx.x >> 6);  // SGPR
  const int bid  = blockIdx.x * 4 + wv;  // ((g*NCHUNK)+ch)*2+half, uniform
  const int half = bid & 1;
  const int ch   = (bid >> 1) & (NCHUNK - 1);
  const int g    = bid >> 5;
  const int h    = g & 31;
  const int b    = (g >> 5) & 1;
  const int dir  = g >> 6;
  const int p    = threadIdx.x & 63;    // 0..63
  const int n0   = half * 32;
  const float Dh = (dir ? bD : fD)[h];
  const int rowbase = dir * 2048 + b * 1024;
  const int t0 = ch * CHUNK;
  ushort* __restrict__ yh = half ? Y1 : Y0;

  float hs[32];
  #pragma unroll
  for (int i = 0; i < 32; ++i) hs[i] = 0.f;
  float P = 1.f;

  // prefetch first x
  int l0 = dir ? (LSEQ - 1 - t0) : t0;
  ushort xr = xs[(size_t)(rowbase + l0) * 2048 + h * 64 + p];

  for (int step = 0; step < CHUNK; ++step) {
    const int tau = t0 + step;
    const int l   = dir ? (LSEQ - 1 - tau) : tau;
    const int row = rowbase + l;
    // prefetch next step's x
    ushort xnext = 0;
    if (step + 1 < CHUNK) {
      const int ln = dir ? (l - 1) : (l + 1);
      xnext = xs[(size_t)(rowbase + ln) * 2048 + h * 64 + p];
    }
    const float dt = dtA[(size_t)row * 64 + h];        // uniform -> s_load
    const float dA = dtA[(size_t)row * 64 + 32 + h];   // uniform -> s_load
    const float* __restrict__ Brow = BC + (size_t)row * 128 + n0;        // uniform
    const float* __restrict__ Crow = BC + (size_t)row * 128 + 64 + n0;   // uniform
    const float xv = bf2f(xr);
    const float a  = dt * xv;
    float yp0 = 0.f, yp1 = 0.f, yp2 = 0.f, yp3 = 0.f;
    #pragma unroll
    for (int n = 0; n < 32; n += 4) {
      hs[n+0] = dA * hs[n+0] + a * Brow[n+0]; yp0 += Crow[n+0] * hs[n+0];
      hs[n+1] = dA * hs[n+1] + a * Brow[n+1]; yp1 += Crow[n+1] * hs[n+1];
      hs[n+2] = dA * hs[n+2] + a * Brow[n+2]; yp2 += Crow[n+2] * hs[n+2];
      hs[n+3] = dA * hs[n+3] + a * Brow[n+3]; yp3 += Crow[n+3] * hs[n+3];
    }
    P *= dA;
    float yp = (yp0 + yp1) + (yp2 + yp3);
    if (half == 0) yp += Dh * xv;       // D-skip term once
    yh[(size_t)row * 2048 + h * 64 + p] = f2bf(yp);
    xr = xnext;
  }

  // write this half's h_end columns (32 contiguous bf16 per lane)
  ushort* dst = hendb + (size_t)(bid >> 1) * 4096 + p * 64 + n0;
  #pragma unroll
  for (int n = 0; n < 32; n += 8) {
    ushort o8[8];
    #pragma unroll
    for (int j = 0; j < 8; ++j) o8[j] = f2bf(hs[n + j]);
    *(int4*)(dst + n) = *(int4*)o8;
  }
  if (half == 0 && p == 0) Afull[g * NCHUNK + ch] = P;
}

// Pass 2: carry h across chunks (elementwise over 4096 state elems, bf16 io).
// Overwrites hendb[g][ch] with h_in(ch) (carry BEFORE chunk ch).
__global__ __launch_bounds__(512) void scan_combine2(
    ushort* __restrict__ hendb, const float* __restrict__ Afull)
{
  const int g   = blockIdx.x;           // 128 groups
  const int off = threadIdx.x * 8;      // 512*8 = 4096 elems
  float ca[8];
  #pragma unroll
  for (int i = 0; i < 8; ++i) ca[i] = 0.f;
  for (int ch = 0; ch < NCHUNK; ++ch) {
    ushort* hb = hendb + (size_t)(g * NCHUNK + ch) * 4096 + off;
    ushort e8[8];
    *(int4*)e8 = *(const int4*)hb;
    ushort o8[8];
    #pragma unroll
    for (int i = 0; i < 8; ++i) o8[i] = f2bf(ca[i]);
    *(int4*)hb = *(int4*)o8;            // h_in for this chunk
    const float A = Afull[g * NCHUNK + ch];
    #pragma unroll
    for (int i = 0; i < 8; ++i) ca[i] = A * ca[i] + bf2f(e8[i]);
  }
}

// Pass 3: y[t] += P_t * (C_t . h_in(chunk)), split by n-half like pass 1.
// 4 waves per block, readfirstlane-uniform wave id; each half-wave RMWs its
// own bf16 Y-half (exclusive rows). P recomputed from uniform dA.
__global__ __launch_bounds__(256, 8) void scan_corr2(
    const float* __restrict__ BC, const ushort* __restrict__ hinb,
    const float* __restrict__ dtA,
    ushort* __restrict__ Y0, ushort* __restrict__ Y1)
{
  const int wv   = __builtin_amdgcn_readfirstlane(threadIdx.x >> 6);  // SGPR
  const int bid  = blockIdx.x * 4 + wv;  // ((g*NCHUNK)+ch)*2+half, uniform
  const int half = bid & 1;
  const int ch   = (bid >> 1) & (NCHUNK - 1);
  if (ch == 0) return;                  // h_in(0) == 0
  const int g    = bid >> 5;
  const int h    = g & 31;
  const int b    = (g >> 5) & 1;
  const int dir  = g >> 6;
  const int p    = threadIdx.x & 63;
  const int n0   = half * 32;
  const int rowbase = dir * 2048 + b * 1024;
  const int t0 = ch * CHUNK;
  ushort* __restrict__ yh = half ? Y1 : Y0;

  float hin[32];
  {
    const ushort* hb = hinb + (size_t)(bid >> 1) * 4096 + p * 64 + n0;
    #pragma unroll
    for (int n = 0; n < 32; n += 8) {
      ushort e8[8];
      *(int4*)e8 = *(const int4*)(hb + n);
      #pragma unroll
      for (int j = 0; j < 8; ++j) hin[n + j] = bf2f(e8[j]);
    }
  }

  float P = 1.f;
  for (int step = 0; step < CHUNK; ++step) {
    const int tau = t0 + step;
    const int l   = dir ? (LSEQ - 1 - tau) : tau;
    const int row = rowbase + l;
    const float dA = dtA[(size_t)row * 64 + 32 + h];   // uniform
    P *= dA;
    const float* __restrict__ Crow = BC + (size_t)row * 128 + 64 + n0;   // uniform
    float s0 = 0.f, s1 = 0.f, s2 = 0.f, s3 = 0.f;
    #pragma unroll
    for (int n = 0; n < 32; n += 4) {
      s0 += Crow[n+0] * hin[n+0];
      s1 += Crow[n+1] * hin[n+1];
      s2 += Crow[n+2] * hin[n+2];
      s3 += Crow[n+3] * hin[n+3];
    }
    const size_t yi = (size_t)row * 2048 + h * 64 + p;
    yh[yi] = f2bf(bf2f(yh[yi]) + ((s0 + s1) + (s2 + s3)) * P);
  }
}

// ---------------- gated RMSNorm: yn = ((Y0+Y1)*silu(z)) * rsqrt(mean sq) * normw
__global__ __launch_bounds__(256) void norm_kernel(
    const ushort* __restrict__ Y0, const ushort* __restrict__ Y1,
    const ushort* __restrict__ zx,
    const float* __restrict__ fnormw, const float* __restrict__ bnormw,
    ushort* __restrict__ yn)
{
  const int bidx = blockIdx.x;          // dir*2048 + row
  const int dir  = bidx >> 11;
  const int tid  = threadIdx.x;
  const float* nw = dir ? bnormw : fnormw;
  const ushort* zrow = zx + (size_t)bidx * DPROJP;
  const int c = tid * 8;
  const size_t yoff = (size_t)bidx * 2048 + c;

  ushort a8[8], b8[8], z8[8];
  *(int4*)a8 = *(const int4*)(Y0 + yoff);
  *(int4*)b8 = *(const int4*)(Y1 + yoff);
  *(int4*)z8 = *(const int4*)(zrow + c);
  float g[8];
  #pragma unroll
  for (int j = 0; j < 8; ++j)
    g[j] = (bf2f(a8[j]) + bf2f(b8[j])) * siluf(bf2f(z8[j]));
  float ss = 0.f;
  #pragma unroll
  for (int j = 0; j < 8; ++j) ss += g[j] * g[j];
  #pragma unroll
  for (int off = 32; off > 0; off >>= 1) ss += __shfl_xor(ss, off);
  __shared__ float red[4];
  const int wid = tid >> 6, lane = tid & 63;
  if (lane == 0) red[wid] = ss;
  __syncthreads();
  const float tot = red[0] + red[1] + red[2] + red[3];
  const float scale = rsqrtf(tot * (1.f / 2048.f) + 1e-5f);
  ushort o8[8];
  #pragma unroll
  for (int j = 0; j < 8; ++j) o8[j] = f2bf(g[j] * scale * nw[c + j]);
  *(int4*)(yn + (size_t)bidx * 2048 + c) = *(int4*)o8;
}

// -------------------------------------------------------------------------------
extern "C" void kernel_launch(void* const* d_in, const int* in_sizes, int n_in,
                              void* d_out, int out_size, void* d_ws, size_t ws_size,
                              hipStream_t stream)
{
  const float* x      = (const float*)d_in[0];
  const float* fWin   = (const float*)d_in[1];
  const float* fconvw = (const float*)d_in[2];
  const float* fconvb = (const float*)d_in[3];
  const float* fdtb   = (const float*)d_in[4];
  const float* fAlog  = (const float*)d_in[5];
  const float* fD     = (const float*)d_in[6];
  const float* fnormw = (const float*)d_in[7];
  const float* fWout  = (const float*)d_in[8];
  const float* bWin   = (const float*)d_in[9];
  const float* bconvw = (const float*)d_in[10];
  const float* bconvb = (const float*)d_in[11];
  const float* bdtb   = (const float*)d_in[12];
  const float* bAlog  = (const float*)d_in[13];
  const float* bD     = (const float*)d_in[14];
  const float* bnormw = (const float*)d_in[15];
  const float* bWout  = (const float*)d_in[16];
  const float* Wo     = (const float*)d_in[17];
  const float* bo     = (const float*)d_in[18];

  char* ws = (char*)d_ws;
  ushort* XB    = (ushort*)(ws);               // x bf16               [2048][1024]
  ushort* WINT  = (ushort*)(ws + 4194304);     // Win^T bf16 (padded)  [2][4352][1024]
  ushort* WOUTT = (ushort*)(ws + 22020096);    // Wout^T bf16          [2][1024][2048]
  ushort* WOT   = (ushort*)(ws + 30408704);    // Wo^T bf16            [1024][2048]
  ushort* ZX    = (ushort*)(ws + 34603008);    // zxbcdt bf16          [2][2048][4352]
  ushort* XS    = (ushort*)(ws + 70254592);    // conv'd x bf16        [2][2048][2048]
  float*  BCB   = (float*) (ws + 87031808);    // B,C f32              [2][2048][128]
  float*  DTA   = (float*) (ws + 89128960);    // dt,dA f32            [2][2048][64]
  ushort* Y0B   = (ushort*)(ws + 90177536);    // y partial n<32 bf16  [2][2048][2048]
  ushort* Y1B   = (ushort*)(ws + 106954752);   // y partial n>=32 bf16 [2][2048][2048]
  ushort* YN    = (ushort*)(ws + 123731968);   // normed bf16          [2][2048][2048]
  ushort* OUT2  = (ushort*)(ws + 140509184);   // concat(fwd,rev) bf16 [2048][2048]
  // HENDB/AFULL alias the WINT region (17.83 MB): WINT is dead after the
  // in-projection GEMM completes; scan_local2 runs strictly after it.
  // Total ws stays at the proven 148,897,792 bytes.
  ushort* HENDB = (ushort*)(ws + 4194304);     // h_end->h_in bf16 [2048][64][64] (16.78 MB)
  float*  AFULL = (float*) (ws + 20971520);    // chunk decay totals [128][16] (8 KB)

  // --- convert / transpose weights & activations to bf16 (B^T layouts) ---
  convert_f32_bf16<<<2048, 256, 0, stream>>>(x, XB, 2048 * 1024);
  transpose_f32_bf16<<<dim3(136, 32), dim3(32, 8), 0, stream>>>(fWin, WINT, 1024, 4256);
  transpose_f32_bf16<<<dim3(136, 32), dim3(32, 8), 0, stream>>>(bWin, WINT + (size_t)4352 * 1024, 1024, 4256);
  transpose_f32_bf16<<<dim3(32, 64),  dim3(32, 8), 0, stream>>>(fWout, WOUTT, 2048, 1024);
  transpose_f32_bf16<<<dim3(32, 64),  dim3(32, 8), 0, stream>>>(bWout, WOUTT + (size_t)1024 * 2048, 2048, 1024);
  transpose_f32_bf16<<<dim3(32, 64),  dim3(32, 8), 0, stream>>>(Wo, WOT, 2048, 1024);

  // --- in-projection, both directions fused via gridDim.z ---
  gemm_bt<1, 0><<<dim3(34, 16, 2), 256, 0, stream>>>(
      XB, WINT, (void*)ZX, nullptr, 2048, 4352, 1024, 4352,
      0, (size_t)4352 * 1024, (size_t)2048 * 4352);

  // --- conv (causal fwd / anti-causal bwd) + silu + dt/dA ---
  conv_prep<<<4096, 256, 0, stream>>>(ZX, fconvw, fconvb, bconvw, bconvb,
                                      fdtb, fAlog, bdtb, bAlog, XS, BCB, DTA);

  // --- chunked selective scan, n-split, 4 waves/block, uniform wave id ---
  scan_local2<<<128 * NCHUNK * 2 / 4, 256, 0, stream>>>(XS, BCB, DTA, fD, bD,
                                                        Y0B, Y1B, HENDB, AFULL);
  scan_combine2<<<128, 512, 0, stream>>>(HENDB, AFULL);
  scan_corr2<<<128 * NCHUNK * 2 / 4, 256, 0, stream>>>(BCB, HENDB, DTA, Y0B, Y1B);

  // --- gated RMSNorm (sums the two y partials) ---
  norm_kernel<<<4096, 256, 0, stream>>>(Y0B, Y1B, ZX, fnormw, bnormw, YN);

  // --- out-projections (both dirs fused) into concat buffer, then final Wo ---
  gemm_bt<1, 0><<<dim3(8, 16, 2), 256, 0, stream>>>(
      YN, WOUTT, (void*)OUT2, nullptr, 2048, 1024, 2048, 2048,
      (size_t)2048 * 2048, (size_t)1024 * 2048, (size_t)1024);
  gemm_bt<0, 1><<<dim3(8, 16), 256, 0, stream>>>(
      OUT2, WOT, d_out, bo, 2048, 1024, 2048, 1024, 0, 0, 0);
}

// Round 10
// 365.783 us; speedup vs baseline: 1.7360x; 1.2578x over previous
//
#include <hip/hip_runtime.h>
#include <hip/hip_bf16.h>
#include <stdint.h>

#define AS1 __attribute__((address_space(1)))
#define AS3 __attribute__((address_space(3)))

typedef short bf16x8 __attribute__((ext_vector_type(8)));
typedef float f32x4 __attribute__((ext_vector_type(4)));

static constexpr int LSEQ   = 1024;
static constexpr int DINNER = 2048;
static constexpr int CCH    = 2176;   // conv channels
static constexpr int DPROJ  = 4256;
static constexpr int DPROJP = 4352;   // padded to 34*128
static constexpr int CHUNK  = 64;     // scan chunk length
static constexpr int NCHUNK = LSEQ / CHUNK;   // 16

__device__ __forceinline__ float bf2f(ushort u) {
  union { uint32_t i; float f; } v; v.i = ((uint32_t)u) << 16; return v.f;
}
__device__ __forceinline__ ushort f2bf(float f) {
  union { float f; uint32_t i; } v; v.f = f;
  uint32_t r = v.i + 0x7fffu + ((v.i >> 16) & 1u);   // RNE
  return (ushort)(r >> 16);
}
__device__ __forceinline__ float siluf(float v) { return v / (1.f + __expf(-v)); }

// ---------------- elementwise f32 -> bf16 ----------------
__global__ void convert_f32_bf16(const float* __restrict__ src, ushort* __restrict__ dst, int n) {
  int i = (blockIdx.x * blockDim.x + threadIdx.x) * 4;
  if (i < n) {
    float4 v = *(const float4*)(src + i);
    ushort4 o; o.x = f2bf(v.x); o.y = f2bf(v.y); o.z = f2bf(v.z); o.w = f2bf(v.w);
    *(ushort4*)(dst + i) = o;
  }
}

// ---------------- transpose f32 [R][C] -> bf16 [Cpad][R], zero-fill pad rows ----
__global__ void transpose_f32_bf16(const float* __restrict__ src, ushort* __restrict__ dst,
                                   int R, int C) {
  __shared__ float tile[32][33];
  int c0 = blockIdx.x * 32, r0 = blockIdx.y * 32;
  int tx = threadIdx.x, ty = threadIdx.y;
  #pragma unroll
  for (int j = 0; j < 4; ++j) {
    int c = c0 + tx, r = r0 + ty + j * 8;
    tile[ty + j * 8][tx] = (c < C) ? src[(size_t)r * C + c] : 0.f;
  }
  __syncthreads();
  #pragma unroll
  for (int j = 0; j < 4; ++j) {
    int cc = c0 + ty + j * 8, rr = r0 + tx;
    dst[(size_t)cc * R + rr] = f2bf(tile[tx][ty + j * 8]);
  }
}

// ---------------- bf16 MFMA GEMM: C[M][N] = A[M][K] * Bt[N][K]^T (+bias) -------
template<int OUT_BF16, int ADD_BIAS>
__global__ __launch_bounds__(256) void gemm_bt(
    const ushort* __restrict__ A, const ushort* __restrict__ Bt,
    void* __restrict__ Cp, const float* __restrict__ bias,
    int M, int N, int K, int ldc,
    size_t sA, size_t sB, size_t sC)
{
  __shared__ char lds[32768];   // 2 bufs x (A 8KB + B 8KB)
  const int tid  = threadIdx.x;
  const int lane = tid & 63;
  const int wid  = tid >> 6;
  const int wm = wid >> 1, wn = wid & 1;
  const int m0 = blockIdx.y * 128, n0 = blockIdx.x * 128;
  const size_t zo = blockIdx.z;
  A  += zo * sA;
  Bt += zo * sB;

  f32x4 acc[4][4];
  {
    f32x4 z = {0.f, 0.f, 0.f, 0.f};
    #pragma unroll
    for (int i = 0; i < 4; ++i)
      #pragma unroll
      for (int j = 0; j < 4; ++j) acc[i][j] = z;
  }

  const int rr = tid >> 2;            // staging row within 64-row half
  const int ce = (tid & 3) * 8;       // staging k-element offset

  auto stage = [&](int buf, int kt) {
    const int k0 = kt * 32;
    char* base = lds + buf * 16384;
    #pragma unroll
    for (int q = 0; q < 2; ++q) {
      const ushort* ga = A + (size_t)(m0 + q * 64 + rr) * K + (k0 + ce);
      __builtin_amdgcn_global_load_lds((AS1 void*)ga,
          (AS3 void*)(base + q * 4096 + wid * 1024), 16, 0, 0);
    }
    #pragma unroll
    for (int q = 0; q < 2; ++q) {
      const ushort* gb = Bt + (size_t)(n0 + q * 64 + rr) * K + (k0 + ce);
      __builtin_amdgcn_global_load_lds((AS1 void*)gb,
          (AS3 void*)(base + 8192 + q * 4096 + wid * 1024), 16, 0, 0);
    }
  };

  auto compute = [&](int buf) {
    const char* base = lds + buf * 16384;
    const int ra = lane & 15;
    const int kb = (lane >> 4) * 16;
    bf16x8 af[4], bfr[4];
    #pragma unroll
    for (int mt = 0; mt < 4; ++mt)
      af[mt] = *(const bf16x8*)(base + (wm * 64 + mt * 16 + ra) * 64 + kb);
    #pragma unroll
    for (int nt = 0; nt < 4; ++nt)
      bfr[nt] = *(const bf16x8*)(base + 8192 + (wn * 64 + nt * 16 + ra) * 64 + kb);
    #pragma unroll
    for (int mt = 0; mt < 4; ++mt)
      #pragma unroll
      for (int nt = 0; nt < 4; ++nt)
        acc[mt][nt] = __builtin_amdgcn_mfma_f32_16x16x32_bf16(af[mt], bfr[nt], acc[mt][nt], 0, 0, 0);
  };

  const int NT = K >> 5;
  stage(0, 0);
  __syncthreads();
  for (int kt = 0; kt < NT; ++kt) {
    if (kt + 1 < NT) stage((kt + 1) & 1, kt + 1);
    compute(kt & 1);
    __syncthreads();
  }

  const int rbase = m0 + wm * 64 + (lane >> 4) * 4;
  const int cbase = n0 + wn * 64 + (lane & 15);
  #pragma unroll
  for (int mt = 0; mt < 4; ++mt) {
    #pragma unroll
    for (int nt = 0; nt < 4; ++nt) {
      const int col = cbase + nt * 16;
      float bv = ADD_BIAS ? bias[col] : 0.f;
      #pragma unroll
      for (int e = 0; e < 4; ++e) {
        const int row = rbase + mt * 16 + e;
        float v = acc[mt][nt][e] + bv;
        if (OUT_BF16) ((ushort*)Cp)[zo * sC + (size_t)row * ldc + col] = f2bf(v);
        else          ((float*) Cp)[zo * sC + (size_t)row * ldc + col] = v;
      }
    }
  }
}

// ---------------- depthwise conv + silu + dt/ldA prep --------------------------
// Writes xs bf16, BCb bf16 [4096][128] (B cols 0-63, C cols 64-127),
// dtA f32 [4096][64]: [0:32] dt, [32:64] ldA = dt * A  (A = -exp(Alog)).
__global__ __launch_bounds__(256) void conv_prep(
    const ushort* __restrict__ zx,
    const float* __restrict__ fconvw, const float* __restrict__ fconvb,
    const float* __restrict__ bconvw, const float* __restrict__ bconvb,
    const float* __restrict__ fdtb, const float* __restrict__ fAlog,
    const float* __restrict__ bdtb, const float* __restrict__ bAlog,
    ushort* __restrict__ xs, ushort* __restrict__ BCb,
    float* __restrict__ dtA)
{
  const int bidx = blockIdx.x;          // dir*2048 + b*1024 + l
  const int dir  = bidx >> 11;
  const int l    = bidx & 1023;
  const int tid  = threadIdx.x;
  const float* convw = dir ? bconvw : fconvw;
  const float* convb = dir ? bconvb : fconvb;

  for (int c = tid; c < CCH; c += 256) {
    float acc = convb[c];
    if (dir == 0) {
      #pragma unroll
      for (int k = 0; k < 4; ++k) {
        int ls = l - 3 + k;
        if (ls >= 0)
          acc += bf2f(zx[(size_t)(bidx - 3 + k) * DPROJP + DINNER + c]) * convw[k * CCH + c];
      }
    } else {
      #pragma unroll
      for (int j = 0; j < 4; ++j) {
        int ls = l + j;
        if (ls < LSEQ)
          acc += bf2f(zx[(size_t)(bidx + j) * DPROJP + DINNER + c]) * convw[(3 - j) * CCH + c];
      }
    }
    float v = siluf(acc);
    if (c < DINNER) xs[(size_t)bidx * 2048 + c] = f2bf(v);
    else            BCb[(size_t)bidx * 128 + (c - DINNER)] = f2bf(v);
  }
  if (tid < 32) {
    const int h = tid;
    float dtb  = dir ? bdtb[h]  : fdtb[h];
    float Alog = dir ? bAlog[h] : fAlog[h];
    float draw = bf2f(zx[(size_t)bidx * DPROJP + 4224 + h]) + dtb;
    float dt = (draw > 15.f) ? draw : log1pf(__expf(draw));
    dtA[(size_t)bidx * 64 + h]      = dt;
    dtA[(size_t)bidx * 64 + 32 + h] = dt * (-__expf(Alog));   // ldA = log(dA)
  }
}

// ---------------- SSD pass 1: per (g,chunk) block, MFMA formulation ------------
// G = C@B^T; M[t,s] = G * exp(S[t]-S[s]) * dt[s] * (s<=t);
// Y_local = M@X (+D-skip); h_end[p][n] = sum_s Xt[p,s] * (w[s]*B[s,n]).
// All LDS tiles slot-swizzled: physical slot sp holds logical slot sp^(row&7).
__global__ __launch_bounds__(256) void scan_ssd1(
    const ushort* __restrict__ xs, const ushort* __restrict__ BCb,
    const float* __restrict__ dtA, const float* __restrict__ fD,
    const float* __restrict__ bD, float* __restrict__ Y,
    ushort* __restrict__ hendb, float* __restrict__ Afull)
{
  __shared__ __align__(16) char lds[49920];
  constexpr int BCcB = 0;       // [64][256B]  B slots 0-7, C slots 8-15
  constexpr int XB_  = 16384;   // [64][128B]  X[s][p]
  constexpr int XtB  = 24576;   // [64][128B]  Xt[p][s]
  constexpr int BwtB = 32768;   // [64][128B]  Bwt[n][s]
  constexpr int MB_  = 40960;   // [64][128B]  M[t][s]
  constexpr int SB   = 49152;   // f32[64]
  constexpr int DTB  = 49408;   // f32[64]
  constexpr int WSB  = 49664;   // f32[64]

  const int bid = blockIdx.x;           // g*NCHUNK + ch
  const int ch  = bid & (NCHUNK - 1);
  const int g   = bid >> 4;
  const int h   = g & 31;
  const int b   = (g >> 5) & 1;
  const int dir = g >> 6;
  const int tid = threadIdx.x;
  const int wv  = tid >> 6;
  const int lane= tid & 63;
  const int t0  = ch * CHUNK;
  const int rowbase = dir * 2048 + b * 1024;
  const float Dh = (dir ? bD : fD)[h];

  auto glrow = [&](int tl) { return rowbase + (dir ? (1023 - (t0 + tl)) : (t0 + tl)); };

  // --- stage BCc (16KB) and X (8KB), scan-time row order, pre-swizzled src ---
  #pragma unroll
  for (int i = 0; i < 4; ++i) {
    int inst = wv * 4 + i;
    int r  = inst * 4 + (lane >> 4);
    int sp = lane & 15;
    const char* src = (const char*)BCb + (size_t)glrow(r) * 256 + (size_t)((sp ^ (r & 7)) * 16);
    __builtin_amdgcn_global_load_lds((AS1 void*)src,
        (AS3 void*)(lds + BCcB + inst * 1024 + lane * 16), 16, 0, 0);
  }
  #pragma unroll
  for (int i = 0; i < 2; ++i) {
    int inst = wv * 2 + i;
    int r  = inst * 8 + (lane >> 3);
    int sp = lane & 7;
    const char* src = (const char*)xs + (size_t)glrow(r) * 4096 + h * 128
                    + (size_t)((sp ^ (r & 7)) * 16);
    __builtin_amdgcn_global_load_lds((AS1 void*)src,
        (AS3 void*)(lds + XB_ + inst * 1024 + lane * 16), 16, 0, 0);
  }

  // --- wave 0: S = prefix(ldA), dt, w[s] = exp(S63-S[s])*dt[s] ---
  if (wv == 0) {
    int gr = glrow(lane);
    float dt  = dtA[(size_t)gr * 64 + h];
    float S   = dtA[(size_t)gr * 64 + 32 + h];
    #pragma unroll
    for (int off = 1; off < 64; off <<= 1) {
      float tv = __shfl_up(S, off);
      if (lane >= off) S += tv;
    }
    float S63 = __shfl(S, 63);
    ((float*)(lds + SB))[lane]  = S;
    ((float*)(lds + DTB))[lane] = dt;
    ((float*)(lds + WSB))[lane] = __expf(S63 - S) * dt;
    if (lane == 63) Afull[g * NCHUNK + ch] = __expf(S);
  }
  __syncthreads();

  // --- build Xt[p][s] and Bwt[n][s] (swizzled scalar writes) ---
  #pragma unroll
  for (int q = 0; q < 2; ++q) {
    int pslot = wv * 2 + q;             // 0..7
    int s = lane;
    bf16x8 v = *(const bf16x8*)(lds + XB_ + s * 128 + ((pslot ^ (s & 7)) * 16));
    #pragma unroll
    for (int j = 0; j < 8; ++j) {
      int p = pslot * 8 + j;
      *(ushort*)(lds + XtB + p * 128 + (((s >> 3) ^ (p & 7)) * 16) + (s & 7) * 2) = (ushort)v[j];
    }
  }
  #pragma unroll
  for (int q = 0; q < 2; ++q) {
    int nslot = wv * 2 + q;
    int s = lane;
    bf16x8 v = *(const bf16x8*)(lds + BCcB + s * 256 + ((nslot ^ (s & 7)) * 16));
    float w = ((const float*)(lds + WSB))[s];
    #pragma unroll
    for (int j = 0; j < 8; ++j) {
      int n = nslot * 8 + j;
      *(ushort*)(lds + BwtB + n * 128 + (((s >> 3) ^ (n & 7)) * 16) + (s & 7) * 2)
          = f2bf(w * bf2f((ushort)v[j]));
    }
  }

  // --- G = Cc @ Bc^T (t-strip = wv*16..), mask -> M (own rows) ---
  {
    f32x4 G[4];
    { f32x4 z = {0,0,0,0}; G[0]=z; G[1]=z; G[2]=z; G[3]=z; }
    const int ra = lane & 15;
    const int k8 = (lane >> 4) * 8;
    #pragma unroll
    for (int k0 = 0; k0 < 64; k0 += 32) {
      int kk = k0 + k8;
      int tA = wv * 16 + ra;
      bf16x8 af = *(const bf16x8*)(lds + BCcB + tA * 256 + ((8 + ((kk >> 3) ^ (tA & 7))) * 16));
      #pragma unroll
      for (int fs = 0; fs < 4; ++fs) {
        int sB = fs * 16 + ra;
        bf16x8 bf = *(const bf16x8*)(lds + BCcB + sB * 256 + (((kk >> 3) ^ (sB & 7)) * 16));
        G[fs] = __builtin_amdgcn_mfma_f32_16x16x32_bf16(af, bf, G[fs], 0, 0, 0);
      }
    }
    const float* Sl  = (const float*)(lds + SB);
    const float* dtl = (const float*)(lds + DTB);
    #pragma unroll
    for (int fs = 0; fs < 4; ++fs) {
      #pragma unroll
      for (int e = 0; e < 4; ++e) {
        int t = wv * 16 + (lane >> 4) * 4 + e;
        int s = fs * 16 + (lane & 15);
        float m = (s <= t) ? (G[fs][e] * __expf(Sl[t] - Sl[s]) * dtl[s]) : 0.f;
        *(ushort*)(lds + MB_ + t * 128 + (((s >> 3) ^ (t & 7)) * 16) + (s & 7) * 2) = f2bf(m);
      }
    }
  }
  __syncthreads();

  // --- Y = M @ X (Bt=Xt), Hend = Xt @ (w.B) (Bt=Bwt) ---
  f32x4 Yf[4], Hf[4];
  { f32x4 z = {0,0,0,0};
    #pragma unroll
    for (int f = 0; f < 4; ++f) { Yf[f] = z; Hf[f] = z; } }
  {
    const int ra = lane & 15;
    const int k8 = (lane >> 4) * 8;
    #pragma unroll
    for (int k0 = 0; k0 < 64; k0 += 32) {
      int kk = k0 + k8;
      int tA = wv * 16 + ra;
      bf16x8 am = *(const bf16x8*)(lds + MB_ + tA * 128 + (((kk >> 3) ^ (tA & 7)) * 16));
      bf16x8 ax = *(const bf16x8*)(lds + XtB + tA * 128 + (((kk >> 3) ^ (tA & 7)) * 16));
      #pragma unroll
      for (int f = 0; f < 4; ++f) {
        int pB = f * 16 + ra;
        bf16x8 bx = *(const bf16x8*)(lds + XtB + pB * 128 + (((kk >> 3) ^ (pB & 7)) * 16));
        Yf[f] = __builtin_amdgcn_mfma_f32_16x16x32_bf16(am, bx, Yf[f], 0, 0, 0);
        bf16x8 bw = *(const bf16x8*)(lds + BwtB + pB * 128 + (((kk >> 3) ^ (pB & 7)) * 16));
        Hf[f] = __builtin_amdgcn_mfma_f32_16x16x32_bf16(ax, bw, Hf[f], 0, 0, 0);
      }
    }
  }

  // --- epilogue: Y (+D-skip) f32 store; h_end bf16 store ---
  #pragma unroll
  for (int f = 0; f < 4; ++f) {
    #pragma unroll
    for (int e = 0; e < 4; ++e) {
      int t = wv * 16 + (lane >> 4) * 4 + e;       // Y row / Hend row (p)
      int c = f * 16 + (lane & 15);                // Y col (p) / Hend col (n)
      float xv = bf2f(*(const ushort*)(lds + XB_ + t * 128
                      + (((c >> 3) ^ (t & 7)) * 16) + (c & 7) * 2));
      Y[(size_t)glrow(t) * 2048 + h * 64 + c] = Yf[f][e] + Dh * xv;
      hendb[(size_t)bid * 4096 + t * 64 + c] = f2bf(Hf[f][e]);
    }
  }
}

// ---------------- pass 2: carry h across chunks (unchanged, bf16 io) -----------
__global__ __launch_bounds__(512) void scan_combine2(
    ushort* __restrict__ hendb, const float* __restrict__ Afull)
{
  const int g   = blockIdx.x;           // 128 groups
  const int off = threadIdx.x * 8;      // 512*8 = 4096 elems
  float ca[8];
  #pragma unroll
  for (int i = 0; i < 8; ++i) ca[i] = 0.f;
  for (int ch = 0; ch < NCHUNK; ++ch) {
    ushort* hb = hendb + (size_t)(g * NCHUNK + ch) * 4096 + off;
    ushort e8[8];
    *(int4*)e8 = *(const int4*)hb;
    ushort o8[8];
    #pragma unroll
    for (int i = 0; i < 8; ++i) o8[i] = f2bf(ca[i]);
    *(int4*)hb = *(int4*)o8;            // h_in for this chunk
    const float A = Afull[g * NCHUNK + ch];
    #pragma unroll
    for (int i = 0; i < 8; ++i) ca[i] = A * ca[i] + bf2f(e8[i]);
  }
}

// ---------------- SSD pass 3: Y[t,p] += exp(S[t]) * (C_t . h_in[p,:]) ----------
__global__ __launch_bounds__(256) void scan_ssd3(
    const ushort* __restrict__ BCb, const ushort* __restrict__ hinb,
    const float* __restrict__ dtA, float* __restrict__ Y)
{
  __shared__ __align__(16) char lds[16640];
  constexpr int CcB = 0;       // [64][128B] C rows
  constexpr int HiB = 8192;    // [64][128B] hin[p][n]
  constexpr int CAB = 16384;   // f32[64] cumA

  const int bid = blockIdx.x;
  const int ch  = bid & (NCHUNK - 1);
  if (ch == 0) return;
  const int g   = bid >> 4;
  const int h   = g & 31;
  const int b   = (g >> 5) & 1;
  const int dir = g >> 6;
  const int tid = threadIdx.x;
  const int wv  = tid >> 6;
  const int lane= tid & 63;
  const int t0  = ch * CHUNK;
  const int rowbase = dir * 2048 + b * 1024;

  auto glrow = [&](int tl) { return rowbase + (dir ? (1023 - (t0 + tl)) : (t0 + tl)); };

  #pragma unroll
  for (int i = 0; i < 2; ++i) {
    int inst = wv * 2 + i;
    int r  = inst * 8 + (lane >> 3);
    int sp = lane & 7;
    const char* src = (const char*)BCb + (size_t)glrow(r) * 256 + 128
                    + (size_t)((sp ^ (r & 7)) * 16);
    __builtin_amdgcn_global_load_lds((AS1 void*)src,
        (AS3 void*)(lds + CcB + inst * 1024 + lane * 16), 16, 0, 0);
  }
  #pragma unroll
  for (int i = 0; i < 2; ++i) {
    int inst = wv * 2 + i;
    int r  = inst * 8 + (lane >> 3);
    int sp = lane & 7;
    const char* src = (const char*)hinb + (size_t)bid * 8192 + (size_t)r * 128
                    + (size_t)((sp ^ (r & 7)) * 16);
    __builtin_amdgcn_global_load_lds((AS1 void*)src,
        (AS3 void*)(lds + HiB + inst * 1024 + lane * 16), 16, 0, 0);
  }
  if (wv == 0) {
    int gr = glrow(lane);
    float S = dtA[(size_t)gr * 64 + 32 + h];
    #pragma unroll
    for (int off = 1; off < 64; off <<= 1) {
      float tv = __shfl_up(S, off);
      if (lane >= off) S += tv;
    }
    ((float*)(lds + CAB))[lane] = __expf(S);
  }
  __syncthreads();

  f32x4 Df[4];
  { f32x4 z = {0,0,0,0}; Df[0]=z; Df[1]=z; Df[2]=z; Df[3]=z; }
  {
    const int ra = lane & 15;
    const int k8 = (lane >> 4) * 8;
    #pragma unroll
    for (int k0 = 0; k0 < 64; k0 += 32) {
      int kk = k0 + k8;
      int tA = wv * 16 + ra;
      bf16x8 ac = *(const bf16x8*)(lds + CcB + tA * 128 + (((kk >> 3) ^ (tA & 7)) * 16));
      #pragma unroll
      for (int f = 0; f < 4; ++f) {
        int pB = f * 16 + ra;
        bf16x8 bh = *(const bf16x8*)(lds + HiB + pB * 128 + (((kk >> 3) ^ (pB & 7)) * 16));
        Df[f] = __builtin_amdgcn_mfma_f32_16x16x32_bf16(ac, bh, Df[f], 0, 0, 0);
      }
    }
  }
  const float* cal = (const float*)(lds + CAB);
  #pragma unroll
  for (int f = 0; f < 4; ++f) {
    #pragma unroll
    for (int e = 0; e < 4; ++e) {
      int t = wv * 16 + (lane >> 4) * 4 + e;
      int p = f * 16 + (lane & 15);
      size_t yi = (size_t)glrow(t) * 2048 + h * 64 + p;
      Y[yi] += cal[t] * Df[f][e];
    }
  }
}

// ---------------- gated RMSNorm: yn = (y*silu(z)) * rsqrt(mean sq) * normw -----
__global__ __launch_bounds__(256) void norm_kernel(
    const float* __restrict__ y, const ushort* __restrict__ zx,
    const float* __restrict__ fnormw, const float* __restrict__ bnormw,
    ushort* __restrict__ yn)
{
  const int bidx = blockIdx.x;          // dir*2048 + row
  const int dir  = bidx >> 11;
  const int tid  = threadIdx.x;
  const float* nw = dir ? bnormw : fnormw;
  const float* yrow  = y  + (size_t)bidx * 2048;
  const ushort* zrow = zx + (size_t)bidx * DPROJP;
  const int c = tid * 8;

  float4 y0 = *(const float4*)(yrow + c);
  float4 y1 = *(const float4*)(yrow + c + 4);
  ushort z8[8];
  *(int4*)z8 = *(const int4*)(zrow + c);
  float g[8];
  g[0] = y0.x * siluf(bf2f(z8[0])); g[1] = y0.y * siluf(bf2f(z8[1]));
  g[2] = y0.z * siluf(bf2f(z8[2])); g[3] = y0.w * siluf(bf2f(z8[3]));
  g[4] = y1.x * siluf(bf2f(z8[4])); g[5] = y1.y * siluf(bf2f(z8[5]));
  g[6] = y1.z * siluf(bf2f(z8[6])); g[7] = y1.w * siluf(bf2f(z8[7]));
  float ss = 0.f;
  #pragma unroll
  for (int j = 0; j < 8; ++j) ss += g[j] * g[j];
  #pragma unroll
  for (int off = 32; off > 0; off >>= 1) ss += __shfl_xor(ss, off);
  __shared__ float red[4];
  const int wid = tid >> 6, lane = tid & 63;
  if (lane == 0) red[wid] = ss;
  __syncthreads();
  const float tot = red[0] + red[1] + red[2] + red[3];
  const float scale = rsqrtf(tot * (1.f / 2048.f) + 1e-5f);
  ushort o8[8];
  #pragma unroll
  for (int j = 0; j < 8; ++j) o8[j] = f2bf(g[j] * scale * nw[c + j]);
  *(int4*)(yn + (size_t)bidx * 2048 + c) = *(int4*)o8;
}

// -------------------------------------------------------------------------------
extern "C" void kernel_launch(void* const* d_in, const int* in_sizes, int n_in,
                              void* d_out, int out_size, void* d_ws, size_t ws_size,
                              hipStream_t stream)
{
  const float* x      = (const float*)d_in[0];
  const float* fWin   = (const float*)d_in[1];
  const float* fconvw = (const float*)d_in[2];
  const float* fconvb = (const float*)d_in[3];
  const float* fdtb   = (const float*)d_in[4];
  const float* fAlog  = (const float*)d_in[5];
  const float* fD     = (const float*)d_in[6];
  const float* fnormw = (const float*)d_in[7];
  const float* fWout  = (const float*)d_in[8];
  const float* bWin   = (const float*)d_in[9];
  const float* bconvw = (const float*)d_in[10];
  const float* bconvb = (const float*)d_in[11];
  const float* bdtb   = (const float*)d_in[12];
  const float* bAlog  = (const float*)d_in[13];
  const float* bD     = (const float*)d_in[14];
  const float* bnormw = (const float*)d_in[15];
  const float* bWout  = (const float*)d_in[16];
  const float* Wo     = (const float*)d_in[17];
  const float* bo     = (const float*)d_in[18];

  char* ws = (char*)d_ws;
  ushort* XB    = (ushort*)(ws);               // x bf16               [2048][1024]
  ushort* WINT  = (ushort*)(ws + 4194304);     // Win^T bf16 (padded)  [2][4352][1024]
  ushort* WOUTT = (ushort*)(ws + 22020096);    // Wout^T bf16          [2][1024][2048]
  ushort* WOT   = (ushort*)(ws + 30408704);    // Wo^T bf16            [1024][2048]
  ushort* ZX    = (ushort*)(ws + 34603008);    // zxbcdt bf16          [2][2048][4352]
  ushort* XS    = (ushort*)(ws + 70254592);    // conv'd x bf16        [2][2048][2048]
  ushort* BCBF  = (ushort*)(ws + 87031808);    // B,C bf16             [4096][128]
  float*  DTA   = (float*) (ws + 89128960);    // dt,ldA f32           [4096][64]
  float*  Y     = (float*) (ws + 90177536);    // scan out f32         [4096][2048]
  ushort* YN    = (ushort*)(ws + 123731968);   // normed bf16          [2][2048][2048]
  ushort* OUT2  = (ushort*)(ws + 140509184);   // concat(fwd,rev) bf16 [2048][2048]
  // HENDB/AFULL alias the WINT region (dead after in-proj GEMM).
  ushort* HENDB = (ushort*)(ws + 4194304);     // h_end->h_in bf16 [2048][64][64]
  float*  AFULL = (float*) (ws + 20971520);    // chunk decay totals [128][16]

  // --- convert / transpose weights & activations to bf16 (B^T layouts) ---
  convert_f32_bf16<<<2048, 256, 0, stream>>>(x, XB, 2048 * 1024);
  transpose_f32_bf16<<<dim3(136, 32), dim3(32, 8), 0, stream>>>(fWin, WINT, 1024, 4256);
  transpose_f32_bf16<<<dim3(136, 32), dim3(32, 8), 0, stream>>>(bWin, WINT + (size_t)4352 * 1024, 1024, 4256);
  transpose_f32_bf16<<<dim3(32, 64),  dim3(32, 8), 0, stream>>>(fWout, WOUTT, 2048, 1024);
  transpose_f32_bf16<<<dim3(32, 64),  dim3(32, 8), 0, stream>>>(bWout, WOUTT + (size_t)1024 * 2048, 2048, 1024);
  transpose_f32_bf16<<<dim3(32, 64),  dim3(32, 8), 0, stream>>>(Wo, WOT, 2048, 1024);

  // --- in-projection, both directions fused via gridDim.z ---
  gemm_bt<1, 0><<<dim3(34, 16, 2), 256, 0, stream>>>(
      XB, WINT, (void*)ZX, nullptr, 2048, 4352, 1024, 4352,
      0, (size_t)4352 * 1024, (size_t)2048 * 4352);

  // --- conv + silu + dt/ldA ---
  conv_prep<<<4096, 256, 0, stream>>>(ZX, fconvw, fconvb, bconvw, bconvb,
                                      fdtb, fAlog, bdtb, bAlog, XS, BCBF, DTA);

  // --- SSD chunked scan: local (MFMA) -> carry -> correction (MFMA) ---
  scan_ssd1<<<2048, 256, 0, stream>>>(XS, BCBF, DTA, fD, bD, Y, HENDB, AFULL);
  scan_combine2<<<128, 512, 0, stream>>>(HENDB, AFULL);
  scan_ssd3<<<2048, 256, 0, stream>>>(BCBF, HENDB, DTA, Y);

  // --- gated RMSNorm ---
  norm_kernel<<<4096, 256, 0, stream>>>(Y, ZX, fnormw, bnormw, YN);

  // --- out-projections (both dirs fused) into concat buffer, then final Wo ---
  gemm_bt<1, 0><<<dim3(8, 16, 2), 256, 0, stream>>>(
      YN, WOUTT, (void*)OUT2, nullptr, 2048, 1024, 2048, 2048,
      (size_t)2048 * 2048, (size_t)1024 * 2048, (size_t)1024);
  gemm_bt<0, 1><<<dim3(8, 16), 256, 0, stream>>>(
      OUT2, WOT, d_out, bo, 2048, 1024, 2048, 1024, 0, 0, 0);
}

// Round 11
// 338.425 us; speedup vs baseline: 1.8764x; 1.0808x over previous
//
#include <hip/hip_runtime.h>
#include <hip/hip_bf16.h>
#include <stdint.h>

#define AS1 __attribute__((address_space(1)))
#define AS3 __attribute__((address_space(3)))

typedef short bf16x8 __attribute__((ext_vector_type(8)));
typedef float f32x4 __attribute__((ext_vector_type(4)));

static constexpr int LSEQ   = 1024;
static constexpr int DINNER = 2048;
static constexpr int CCH    = 2176;   // conv channels
static constexpr int DPROJ  = 4256;
static constexpr int DPROJP = 4352;   // padded to 34*128
static constexpr int CHUNK  = 64;     // scan chunk length
static constexpr int NCHUNK = LSEQ / CHUNK;   // 16

__device__ __forceinline__ float bf2f(ushort u) {
  union { uint32_t i; float f; } v; v.i = ((uint32_t)u) << 16; return v.f;
}
__device__ __forceinline__ ushort f2bf(float f) {
  union { float f; uint32_t i; } v; v.f = f;
  uint32_t r = v.i + 0x7fffu + ((v.i >> 16) & 1u);   // RNE
  return (ushort)(r >> 16);
}
__device__ __forceinline__ float siluf(float v) { return v / (1.f + __expf(-v)); }

// ---------------- elementwise f32 -> bf16 ----------------
__global__ void convert_f32_bf16(const float* __restrict__ src, ushort* __restrict__ dst, int n) {
  int i = (blockIdx.x * blockDim.x + threadIdx.x) * 4;
  if (i < n) {
    float4 v = *(const float4*)(src + i);
    ushort4 o; o.x = f2bf(v.x); o.y = f2bf(v.y); o.z = f2bf(v.z); o.w = f2bf(v.w);
    *(ushort4*)(dst + i) = o;
  }
}

// ---------------- transpose f32 [R][C] -> bf16 [Cpad][R], zero-fill pad rows ----
__global__ void transpose_f32_bf16(const float* __restrict__ src, ushort* __restrict__ dst,
                                   int R, int C) {
  __shared__ float tile[32][33];
  int c0 = blockIdx.x * 32, r0 = blockIdx.y * 32;
  int tx = threadIdx.x, ty = threadIdx.y;
  #pragma unroll
  for (int j = 0; j < 4; ++j) {
    int c = c0 + tx, r = r0 + ty + j * 8;
    tile[ty + j * 8][tx] = (c < C) ? src[(size_t)r * C + c] : 0.f;
  }
  __syncthreads();
  #pragma unroll
  for (int j = 0; j < 4; ++j) {
    int cc = c0 + ty + j * 8, rr = r0 + tx;
    dst[(size_t)cc * R + rr] = f2bf(tile[tx][ty + j * 8]);
  }
}

// ---------------- bf16 MFMA GEMM: C[M][N] = A[M][K] * Bt[N][K]^T (+bias) -------
// 128x128 tile, BK=32, 4 waves (2x2), double-buffered LDS via global_load_lds.
// XCD-chunked swizzle: dispatch-linear L -> nl=(L%8)*(nwg/8)+L/8, decoded
// m-fastest so each XCD owns a few B-panels (fits its private L2).
template<int OUT_BF16, int ADD_BIAS>
__global__ __launch_bounds__(256) void gemm_bt(
    const ushort* __restrict__ A, const ushort* __restrict__ Bt,
    void* __restrict__ Cp, const float* __restrict__ bias,
    int M, int N, int K, int ldc,
    size_t sA, size_t sB, size_t sC)
{
  __shared__ char lds[32768];   // 2 bufs x (A 8KB + B 8KB)
  const int tid  = threadIdx.x;
  const int lane = tid & 63;
  const int wid  = tid >> 6;
  const int wm = wid >> 1, wn = wid & 1;

  // --- XCD-chunked remap (nwg divisible by 8 for all our grids) ---
  const int nwg = gridDim.x * gridDim.y * gridDim.z;
  const int L   = blockIdx.x + gridDim.x * (blockIdx.y + gridDim.y * blockIdx.z);
  const int nl  = (L & 7) * (nwg >> 3) + (L >> 3);
  const int my  = nl % gridDim.y;             // m-tile (fastest: A reuse in-chunk)
  const int rest= nl / gridDim.y;
  const int nx  = rest % gridDim.x;           // n-panel
  const size_t zo = rest / gridDim.x;         // dir slice

  const int m0 = my * 128, n0 = nx * 128;
  A  += zo * sA;
  Bt += zo * sB;

  f32x4 acc[4][4];
  {
    f32x4 z = {0.f, 0.f, 0.f, 0.f};
    #pragma unroll
    for (int i = 0; i < 4; ++i)
      #pragma unroll
      for (int j = 0; j < 4; ++j) acc[i][j] = z;
  }

  const int rr = tid >> 2;            // staging row within 64-row half
  const int ce = (tid & 3) * 8;       // staging k-element offset

  auto stage = [&](int buf, int kt) {
    const int k0 = kt * 32;
    char* base = lds + buf * 16384;
    #pragma unroll
    for (int q = 0; q < 2; ++q) {
      const ushort* ga = A + (size_t)(m0 + q * 64 + rr) * K + (k0 + ce);
      __builtin_amdgcn_global_load_lds((AS1 void*)ga,
          (AS3 void*)(base + q * 4096 + wid * 1024), 16, 0, 0);
    }
    #pragma unroll
    for (int q = 0; q < 2; ++q) {
      const ushort* gb = Bt + (size_t)(n0 + q * 64 + rr) * K + (k0 + ce);
      __builtin_amdgcn_global_load_lds((AS1 void*)gb,
          (AS3 void*)(base + 8192 + q * 4096 + wid * 1024), 16, 0, 0);
    }
  };

  auto compute = [&](int buf) {
    const char* base = lds + buf * 16384;
    const int ra = lane & 15;
    const int kb = (lane >> 4) * 16;
    bf16x8 af[4], bfr[4];
    #pragma unroll
    for (int mt = 0; mt < 4; ++mt)
      af[mt] = *(const bf16x8*)(base + (wm * 64 + mt * 16 + ra) * 64 + kb);
    #pragma unroll
    for (int nt = 0; nt < 4; ++nt)
      bfr[nt] = *(const bf16x8*)(base + 8192 + (wn * 64 + nt * 16 + ra) * 64 + kb);
    #pragma unroll
    for (int mt = 0; mt < 4; ++mt)
      #pragma unroll
      for (int nt = 0; nt < 4; ++nt)
        acc[mt][nt] = __builtin_amdgcn_mfma_f32_16x16x32_bf16(af[mt], bfr[nt], acc[mt][nt], 0, 0, 0);
  };

  const int NT = K >> 5;
  stage(0, 0);
  __syncthreads();
  for (int kt = 0; kt < NT; ++kt) {
    if (kt + 1 < NT) stage((kt + 1) & 1, kt + 1);
    compute(kt & 1);
    __syncthreads();
  }

  const int rbase = m0 + wm * 64 + (lane >> 4) * 4;
  const int cbase = n0 + wn * 64 + (lane & 15);
  #pragma unroll
  for (int mt = 0; mt < 4; ++mt) {
    #pragma unroll
    for (int nt = 0; nt < 4; ++nt) {
      const int col = cbase + nt * 16;
      float bv = ADD_BIAS ? bias[col] : 0.f;
      #pragma unroll
      for (int e = 0; e < 4; ++e) {
        const int row = rbase + mt * 16 + e;
        float v = acc[mt][nt][e] + bv;
        if (OUT_BF16) ((ushort*)Cp)[zo * sC + (size_t)row * ldc + col] = f2bf(v);
        else          ((float*) Cp)[zo * sC + (size_t)row * ldc + col] = v;
      }
    }
  }
}

// ---------------- depthwise conv + silu + dt/ldA prep (vectorized bf16x8) ------
// 272 groups of 8 channels; thread tid does group tid (and 256+tid if tid<16).
// Writes xs bf16, BCb bf16 [4096][128], dtA f32 [4096][64]: dt | ldA = dt*A.
__global__ __launch_bounds__(256) void conv_prep(
    const ushort* __restrict__ zx,
    const float* __restrict__ fconvw, const float* __restrict__ fconvb,
    const float* __restrict__ bconvw, const float* __restrict__ bconvb,
    const float* __restrict__ fdtb, const float* __restrict__ fAlog,
    const float* __restrict__ bdtb, const float* __restrict__ bAlog,
    ushort* __restrict__ xs, ushort* __restrict__ BCb,
    float* __restrict__ dtA)
{
  const int bidx = blockIdx.x;          // dir*2048 + b*1024 + l
  const int dir  = bidx >> 11;
  const int l    = bidx & 1023;
  const int tid  = threadIdx.x;
  const float* convw = dir ? bconvw : fconvw;
  const float* convb = dir ? bconvb : fconvb;

  for (int g = tid; g < 272; g += 256) {
    const int c0 = g * 8;
    float acc[8];
    {
      float4 cb0 = *(const float4*)(convb + c0);
      float4 cb1 = *(const float4*)(convb + c0 + 4);
      acc[0]=cb0.x; acc[1]=cb0.y; acc[2]=cb0.z; acc[3]=cb0.w;
      acc[4]=cb1.x; acc[5]=cb1.y; acc[6]=cb1.z; acc[7]=cb1.w;
    }
    #pragma unroll
    for (int k = 0; k < 4; ++k) {
      int rowoff, wk;
      if (dir == 0) { rowoff = -3 + k; wk = k; }
      else          { rowoff = k;      wk = 3 - k; }
      const int ls = l + rowoff;
      if (ls >= 0 && ls < LSEQ) {
        bf16x8 v = *(const bf16x8*)(zx + (size_t)(bidx + rowoff) * DPROJP + DINNER + c0);
        float4 w0 = *(const float4*)(convw + wk * CCH + c0);
        float4 w1 = *(const float4*)(convw + wk * CCH + c0 + 4);
        acc[0] += bf2f((ushort)v[0]) * w0.x; acc[1] += bf2f((ushort)v[1]) * w0.y;
        acc[2] += bf2f((ushort)v[2]) * w0.z; acc[3] += bf2f((ushort)v[3]) * w0.w;
        acc[4] += bf2f((ushort)v[4]) * w1.x; acc[5] += bf2f((ushort)v[5]) * w1.y;
        acc[6] += bf2f((ushort)v[6]) * w1.z; acc[7] += bf2f((ushort)v[7]) * w1.w;
      }
    }
    ushort o8[8];
    #pragma unroll
    for (int j = 0; j < 8; ++j) o8[j] = f2bf(siluf(acc[j]));
    if (c0 < DINNER) *(int4*)(xs  + (size_t)bidx * 2048 + c0)            = *(int4*)o8;
    else             *(int4*)(BCb + (size_t)bidx * 128 + (c0 - DINNER))  = *(int4*)o8;
  }
  if (tid < 32) {
    const int h = tid;
    float dtb  = dir ? bdtb[h]  : fdtb[h];
    float Alog = dir ? bAlog[h] : fAlog[h];
    float draw = bf2f(zx[(size_t)bidx * DPROJP + 4224 + h]) + dtb;
    float dt = (draw > 15.f) ? draw : log1pf(__expf(draw));
    dtA[(size_t)bidx * 64 + h]      = dt;
    dtA[(size_t)bidx * 64 + 32 + h] = dt * (-__expf(Alog));   // ldA = log(dA)
  }
}

// ---------------- SSD pass 1: per (g,chunk) block, MFMA formulation ------------
// G = C@B^T; M[t,s] = G * exp(S[t]-S[s]) * dt[s] * (s<=t);
// Y_local = M@X (+D-skip); h_end[p][n] = sum_s Xt[p,s] * (w[s]*B[s,n]).
// All LDS tiles slot-swizzled: physical slot sp holds logical slot sp^(row&7).
__global__ __launch_bounds__(256) void scan_ssd1(
    const ushort* __restrict__ xs, const ushort* __restrict__ BCb,
    const float* __restrict__ dtA, const float* __restrict__ fD,
    const float* __restrict__ bD, float* __restrict__ Y,
    ushort* __restrict__ hendb, float* __restrict__ Afull)
{
  __shared__ __align__(16) char lds[49920];
  constexpr int BCcB = 0;       // [64][256B]  B slots 0-7, C slots 8-15
  constexpr int XB_  = 16384;   // [64][128B]  X[s][p]
  constexpr int XtB  = 24576;   // [64][128B]  Xt[p][s]
  constexpr int BwtB = 32768;   // [64][128B]  Bwt[n][s]
  constexpr int MB_  = 40960;   // [64][128B]  M[t][s]
  constexpr int SB   = 49152;   // f32[64]
  constexpr int DTB  = 49408;   // f32[64]
  constexpr int WSB  = 49664;   // f32[64]

  const int bid = blockIdx.x;           // g*NCHUNK + ch
  const int ch  = bid & (NCHUNK - 1);
  const int g   = bid >> 4;
  const int h   = g & 31;
  const int b   = (g >> 5) & 1;
  const int dir = g >> 6;
  const int tid = threadIdx.x;
  const int wv  = tid >> 6;
  const int lane= tid & 63;
  const int t0  = ch * CHUNK;
  const int rowbase = dir * 2048 + b * 1024;
  const float Dh = (dir ? bD : fD)[h];

  auto glrow = [&](int tl) { return rowbase + (dir ? (1023 - (t0 + tl)) : (t0 + tl)); };

  // --- stage BCc (16KB) and X (8KB), scan-time row order, pre-swizzled src ---
  #pragma unroll
  for (int i = 0; i < 4; ++i) {
    int inst = wv * 4 + i;
    int r  = inst * 4 + (lane >> 4);
    int sp = lane & 15;
    const char* src = (const char*)BCb + (size_t)glrow(r) * 256 + (size_t)((sp ^ (r & 7)) * 16);
    __builtin_amdgcn_global_load_lds((AS1 void*)src,
        (AS3 void*)(lds + BCcB + inst * 1024 + lane * 16), 16, 0, 0);
  }
  #pragma unroll
  for (int i = 0; i < 2; ++i) {
    int inst = wv * 2 + i;
    int r  = inst * 8 + (lane >> 3);
    int sp = lane & 7;
    const char* src = (const char*)xs + (size_t)glrow(r) * 4096 + h * 128
                    + (size_t)((sp ^ (r & 7)) * 16);
    __builtin_amdgcn_global_load_lds((AS1 void*)src,
        (AS3 void*)(lds + XB_ + inst * 1024 + lane * 16), 16, 0, 0);
  }

  // --- wave 0: S = prefix(ldA), dt, w[s] = exp(S63-S[s])*dt[s] ---
  if (wv == 0) {
    int gr = glrow(lane);
    float dt  = dtA[(size_t)gr * 64 + h];
    float S   = dtA[(size_t)gr * 64 + 32 + h];
    #pragma unroll
    for (int off = 1; off < 64; off <<= 1) {
      float tv = __shfl_up(S, off);
      if (lane >= off) S += tv;
    }
    float S63 = __shfl(S, 63);
    ((float*)(lds + SB))[lane]  = S;
    ((float*)(lds + DTB))[lane] = dt;
    ((float*)(lds + WSB))[lane] = __expf(S63 - S) * dt;
    if (lane == 63) Afull[g * NCHUNK + ch] = __expf(S);
  }
  __syncthreads();

  // --- build Xt[p][s] and Bwt[n][s] (swizzled scalar writes) ---
  #pragma unroll
  for (int q = 0; q < 2; ++q) {
    int pslot = wv * 2 + q;             // 0..7
    int s = lane;
    bf16x8 v = *(const bf16x8*)(lds + XB_ + s * 128 + ((pslot ^ (s & 7)) * 16));
    #pragma unroll
    for (int j = 0; j < 8; ++j) {
      int p = pslot * 8 + j;
      *(ushort*)(lds + XtB + p * 128 + (((s >> 3) ^ (p & 7)) * 16) + (s & 7) * 2) = (ushort)v[j];
    }
  }
  #pragma unroll
  for (int q = 0; q < 2; ++q) {
    int nslot = wv * 2 + q;
    int s = lane;
    bf16x8 v = *(const bf16x8*)(lds + BCcB + s * 256 + ((nslot ^ (s & 7)) * 16));
    float w = ((const float*)(lds + WSB))[s];
    #pragma unroll
    for (int j = 0; j < 8; ++j) {
      int n = nslot * 8 + j;
      *(ushort*)(lds + BwtB + n * 128 + (((s >> 3) ^ (n & 7)) * 16) + (s & 7) * 2)
          = f2bf(w * bf2f((ushort)v[j]));
    }
  }

  // --- G = Cc @ Bc^T (t-strip = wv*16..), mask -> M (own rows) ---
  {
    f32x4 G[4];
    { f32x4 z = {0,0,0,0}; G[0]=z; G[1]=z; G[2]=z; G[3]=z; }
    const int ra = lane & 15;
    const int k8 = (lane >> 4) * 8;
    #pragma unroll
    for (int k0 = 0; k0 < 64; k0 += 32) {
      int kk = k0 + k8;
      int tA = wv * 16 + ra;
      bf16x8 af = *(const bf16x8*)(lds + BCcB + tA * 256 + ((8 + ((kk >> 3) ^ (tA & 7))) * 16));
      #pragma unroll
      for (int fs = 0; fs < 4; ++fs) {
        int sB = fs * 16 + ra;
        bf16x8 bf = *(const bf16x8*)(lds + BCcB + sB * 256 + (((kk >> 3) ^ (sB & 7)) * 16));
        G[fs] = __builtin_amdgcn_mfma_f32_16x16x32_bf16(af, bf, G[fs], 0, 0, 0);
      }
    }
    const float* Sl  = (const float*)(lds + SB);
    const float* dtl = (const float*)(lds + DTB);
    #pragma unroll
    for (int fs = 0; fs < 4; ++fs) {
      #pragma unroll
      for (int e = 0; e < 4; ++e) {
        int t = wv * 16 + (lane >> 4) * 4 + e;
        int s = fs * 16 + (lane & 15);
        float m = (s <= t) ? (G[fs][e] * __expf(Sl[t] - Sl[s]) * dtl[s]) : 0.f;
        *(ushort*)(lds + MB_ + t * 128 + (((s >> 3) ^ (t & 7)) * 16) + (s & 7) * 2) = f2bf(m);
      }
    }
  }
  __syncthreads();

  // --- Y = M @ X (Bt=Xt), Hend = Xt @ (w.B) (Bt=Bwt) ---
  f32x4 Yf[4], Hf[4];
  { f32x4 z = {0,0,0,0};
    #pragma unroll
    for (int f = 0; f < 4; ++f) { Yf[f] = z; Hf[f] = z; } }
  {
    const int ra = lane & 15;
    const int k8 = (lane >> 4) * 8;
    #pragma unroll
    for (int k0 = 0; k0 < 64; k0 += 32) {
      int kk = k0 + k8;
      int tA = wv * 16 + ra;
      bf16x8 am = *(const bf16x8*)(lds + MB_ + tA * 128 + (((kk >> 3) ^ (tA & 7)) * 16));
      bf16x8 ax = *(const bf16x8*)(lds + XtB + tA * 128 + (((kk >> 3) ^ (tA & 7)) * 16));
      #pragma unroll
      for (int f = 0; f < 4; ++f) {
        int pB = f * 16 + ra;
        bf16x8 bx = *(const bf16x8*)(lds + XtB + pB * 128 + (((kk >> 3) ^ (pB & 7)) * 16));
        Yf[f] = __builtin_amdgcn_mfma_f32_16x16x32_bf16(am, bx, Yf[f], 0, 0, 0);
        bf16x8 bw = *(const bf16x8*)(lds + BwtB + pB * 128 + (((kk >> 3) ^ (pB & 7)) * 16));
        Hf[f] = __builtin_amdgcn_mfma_f32_16x16x32_bf16(ax, bw, Hf[f], 0, 0, 0);
      }
    }
  }

  // --- epilogue: Y (+D-skip) f32 store; h_end bf16 store ---
  #pragma unroll
  for (int f = 0; f < 4; ++f) {
    #pragma unroll
    for (int e = 0; e < 4; ++e) {
      int t = wv * 16 + (lane >> 4) * 4 + e;       // Y row / Hend row (p)
      int c = f * 16 + (lane & 15);                // Y col (p) / Hend col (n)
      float xv = bf2f(*(const ushort*)(lds + XB_ + t * 128
                      + (((c >> 3) ^ (t & 7)) * 16) + (c & 7) * 2));
      Y[(size_t)glrow(t) * 2048 + h * 64 + c] = Yf[f][e] + Dh * xv;
      hendb[(size_t)bid * 4096 + t * 64 + c] = f2bf(Hf[f][e]);
    }
  }
}

// ---------------- pass 2: carry h across chunks (unchanged, bf16 io) -----------
__global__ __launch_bounds__(512) void scan_combine2(
    ushort* __restrict__ hendb, const float* __restrict__ Afull)
{
  const int g   = blockIdx.x;           // 128 groups
  const int off = threadIdx.x * 8;      // 512*8 = 4096 elems
  float ca[8];
  #pragma unroll
  for (int i = 0; i < 8; ++i) ca[i] = 0.f;
  for (int ch = 0; ch < NCHUNK; ++ch) {
    ushort* hb = hendb + (size_t)(g * NCHUNK + ch) * 4096 + off;
    ushort e8[8];
    *(int4*)e8 = *(const int4*)hb;
    ushort o8[8];
    #pragma unroll
    for (int i = 0; i < 8; ++i) o8[i] = f2bf(ca[i]);
    *(int4*)hb = *(int4*)o8;            // h_in for this chunk
    const float A = Afull[g * NCHUNK + ch];
    #pragma unroll
    for (int i = 0; i < 8; ++i) ca[i] = A * ca[i] + bf2f(e8[i]);
  }
}

// ---------------- SSD pass 3: Y[t,p] += exp(S[t]) * (C_t . h_in[p,:]) ----------
__global__ __launch_bounds__(256) void scan_ssd3(
    const ushort* __restrict__ BCb, const ushort* __restrict__ hinb,
    const float* __restrict__ dtA, float* __restrict__ Y)
{
  __shared__ __align__(16) char lds[16640];
  constexpr int CcB = 0;       // [64][128B] C rows
  constexpr int HiB = 8192;    // [64][128B] hin[p][n]
  constexpr int CAB = 16384;   // f32[64] cumA

  const int bid = blockIdx.x;
  const int ch  = bid & (NCHUNK - 1);
  if (ch == 0) return;
  const int g   = bid >> 4;
  const int h   = g & 31;
  const int b   = (g >> 5) & 1;
  const int dir = g >> 6;
  const int tid = threadIdx.x;
  const int wv  = tid >> 6;
  const int lane= tid & 63;
  const int t0  = ch * CHUNK;
  const int rowbase = dir * 2048 + b * 1024;

  auto glrow = [&](int tl) { return rowbase + (dir ? (1023 - (t0 + tl)) : (t0 + tl)); };

  #pragma unroll
  for (int i = 0; i < 2; ++i) {
    int inst = wv * 2 + i;
    int r  = inst * 8 + (lane >> 3);
    int sp = lane & 7;
    const char* src = (const char*)BCb + (size_t)glrow(r) * 256 + 128
                    + (size_t)((sp ^ (r & 7)) * 16);
    __builtin_amdgcn_global_load_lds((AS1 void*)src,
        (AS3 void*)(lds + CcB + inst * 1024 + lane * 16), 16, 0, 0);
  }
  #pragma unroll
  for (int i = 0; i < 2; ++i) {
    int inst = wv * 2 + i;
    int r  = inst * 8 + (lane >> 3);
    int sp = lane & 7;
    const char* src = (const char*)hinb + (size_t)bid * 8192 + (size_t)r * 128
                    + (size_t)((sp ^ (r & 7)) * 16);
    __builtin_amdgcn_global_load_lds((AS1 void*)src,
        (AS3 void*)(lds + HiB + inst * 1024 + lane * 16), 16, 0, 0);
  }
  if (wv == 0) {
    int gr = glrow(lane);
    float S = dtA[(size_t)gr * 64 + 32 + h];
    #pragma unroll
    for (int off = 1; off < 64; off <<= 1) {
      float tv = __shfl_up(S, off);
      if (lane >= off) S += tv;
    }
    ((float*)(lds + CAB))[lane] = __expf(S);
  }
  __syncthreads();

  f32x4 Df[4];
  { f32x4 z = {0,0,0,0}; Df[0]=z; Df[1]=z; Df[2]=z; Df[3]=z; }
  {
    const int ra = lane & 15;
    const int k8 = (lane >> 4) * 8;
    #pragma unroll
    for (int k0 = 0; k0 < 64; k0 += 32) {
      int kk = k0 + k8;
      int tA = wv * 16 + ra;
      bf16x8 ac = *(const bf16x8*)(lds + CcB + tA * 128 + (((kk >> 3) ^ (tA & 7)) * 16));
      #pragma unroll
      for (int f = 0; f < 4; ++f) {
        int pB = f * 16 + ra;
        bf16x8 bh = *(const bf16x8*)(lds + HiB + pB * 128 + (((kk >> 3) ^ (pB & 7)) * 16));
        Df[f] = __builtin_amdgcn_mfma_f32_16x16x32_bf16(ac, bh, Df[f], 0, 0, 0);
      }
    }
  }
  const float* cal = (const float*)(lds + CAB);
  #pragma unroll
  for (int f = 0; f < 4; ++f) {
    #pragma unroll
    for (int e = 0; e < 4; ++e) {
      int t = wv * 16 + (lane >> 4) * 4 + e;
      int p = f * 16 + (lane & 15);
      size_t yi = (size_t)glrow(t) * 2048 + h * 64 + p;
      Y[yi] += cal[t] * Df[f][e];
    }
  }
}

// ---------------- gated RMSNorm: yn = (y*silu(z)) * rsqrt(mean sq) * normw -----
__global__ __launch_bounds__(256) void norm_kernel(
    const float* __restrict__ y, const ushort* __restrict__ zx,
    const float* __restrict__ fnormw, const float* __restrict__ bnormw,
    ushort* __restrict__ yn)
{
  const int bidx = blockIdx.x;          // dir*2048 + row
  const int dir  = bidx >> 11;
  const int tid  = threadIdx.x;
  const float* nw = dir ? bnormw : fnormw;
  const float* yrow  = y  + (size_t)bidx * 2048;
  const ushort* zrow = zx + (size_t)bidx * DPROJP;
  const int c = tid * 8;

  float4 y0 = *(const float4*)(yrow + c);
  float4 y1 = *(const float4*)(yrow + c + 4);
  ushort z8[8];
  *(int4*)z8 = *(const int4*)(zrow + c);
  float g[8];
  g[0] = y0.x * siluf(bf2f(z8[0])); g[1] = y0.y * siluf(bf2f(z8[1]));
  g[2] = y0.z * siluf(bf2f(z8[2])); g[3] = y0.w * siluf(bf2f(z8[3]));
  g[4] = y1.x * siluf(bf2f(z8[4])); g[5] = y1.y * siluf(bf2f(z8[5]));
  g[6] = y1.z * siluf(bf2f(z8[6])); g[7] = y1.w * siluf(bf2f(z8[7]));
  float ss = 0.f;
  #pragma unroll
  for (int j = 0; j < 8; ++j) ss += g[j] * g[j];
  #pragma unroll
  for (int off = 32; off > 0; off >>= 1) ss += __shfl_xor(ss, off);
  __shared__ float red[4];
  const int wid = tid >> 6, lane = tid & 63;
  if (lane == 0) red[wid] = ss;
  __syncthreads();
  const float tot = red[0] + red[1] + red[2] + red[3];
  const float scale = rsqrtf(tot * (1.f / 2048.f) + 1e-5f);
  ushort o8[8];
  #pragma unroll
  for (int j = 0; j < 8; ++j) o8[j] = f2bf(g[j] * scale * nw[c + j]);
  *(int4*)(yn + (size_t)bidx * 2048 + c) = *(int4*)o8;
}

// -------------------------------------------------------------------------------
extern "C" void kernel_launch(void* const* d_in, const int* in_sizes, int n_in,
                              void* d_out, int out_size, void* d_ws, size_t ws_size,
                              hipStream_t stream)
{
  const float* x      = (const float*)d_in[0];
  const float* fWin   = (const float*)d_in[1];
  const float* fconvw = (const float*)d_in[2];
  const float* fconvb = (const float*)d_in[3];
  const float* fdtb   = (const float*)d_in[4];
  const float* fAlog  = (const float*)d_in[5];
  const float* fD     = (const float*)d_in[6];
  const float* fnormw = (const float*)d_in[7];
  const float* fWout  = (const float*)d_in[8];
  const float* bWin   = (const float*)d_in[9];
  const float* bconvw = (const float*)d_in[10];
  const float* bconvb = (const float*)d_in[11];
  const float* bdtb   = (const float*)d_in[12];
  const float* bAlog  = (const float*)d_in[13];
  const float* bD     = (const float*)d_in[14];
  const float* bnormw = (const float*)d_in[15];
  const float* bWout  = (const float*)d_in[16];
  const float* Wo     = (const float*)d_in[17];
  const float* bo     = (const float*)d_in[18];

  char* ws = (char*)d_ws;
  ushort* XB    = (ushort*)(ws);               // x bf16               [2048][1024]
  ushort* WINT  = (ushort*)(ws + 4194304);     // Win^T bf16 (padded)  [2][4352][1024]
  ushort* WOUTT = (ushort*)(ws + 22020096);    // Wout^T bf16          [2][1024][2048]
  ushort* WOT   = (ushort*)(ws + 30408704);    // Wo^T bf16            [1024][2048]
  ushort* ZX    = (ushort*)(ws + 34603008);    // zxbcdt bf16          [2][2048][4352]
  ushort* XS    = (ushort*)(ws + 70254592);    // conv'd x bf16        [2][2048][2048]
  ushort* BCBF  = (ushort*)(ws + 87031808);    // B,C bf16             [4096][128]
  float*  DTA   = (float*) (ws + 89128960);    // dt,ldA f32           [4096][64]
  float*  Y     = (float*) (ws + 90177536);    // scan out f32         [4096][2048]
  ushort* YN    = (ushort*)(ws + 123731968);   // normed bf16          [2][2048][2048]
  ushort* OUT2  = (ushort*)(ws + 140509184);   // concat(fwd,rev) bf16 [2048][2048]
  // HENDB/AFULL alias the WINT region (dead after in-proj GEMM).
  ushort* HENDB = (ushort*)(ws + 4194304);     // h_end->h_in bf16 [2048][64][64]
  float*  AFULL = (float*) (ws + 20971520);    // chunk decay totals [128][16]

  // --- convert / transpose weights & activations to bf16 (B^T layouts) ---
  convert_f32_bf16<<<2048, 256, 0, stream>>>(x, XB, 2048 * 1024);
  transpose_f32_bf16<<<dim3(136, 32), dim3(32, 8), 0, stream>>>(fWin, WINT, 1024, 4256);
  transpose_f32_bf16<<<dim3(136, 32), dim3(32, 8), 0, stream>>>(bWin, WINT + (size_t)4352 * 1024, 1024, 4256);
  transpose_f32_bf16<<<dim3(32, 64),  dim3(32, 8), 0, stream>>>(fWout, WOUTT, 2048, 1024);
  transpose_f32_bf16<<<dim3(32, 64),  dim3(32, 8), 0, stream>>>(bWout, WOUTT + (size_t)1024 * 2048, 2048, 1024);
  transpose_f32_bf16<<<dim3(32, 64),  dim3(32, 8), 0, stream>>>(Wo, WOT, 2048, 1024);

  // --- in-projection, both directions fused via gridDim.z ---
  gemm_bt<1, 0><<<dim3(34, 16, 2), 256, 0, stream>>>(
      XB, WINT, (void*)ZX, nullptr, 2048, 4352, 1024, 4352,
      0, (size_t)4352 * 1024, (size_t)2048 * 4352);

  // --- conv + silu + dt/ldA (vectorized) ---
  conv_prep<<<4096, 256, 0, stream>>>(ZX, fconvw, fconvb, bconvw, bconvb,
                                      fdtb, fAlog, bdtb, bAlog, XS, BCBF, DTA);

  // --- SSD chunked scan: local (MFMA) -> carry -> correction (MFMA) ---
  scan_ssd1<<<2048, 256, 0, stream>>>(XS, BCBF, DTA, fD, bD, Y, HENDB, AFULL);
  scan_combine2<<<128, 512, 0, stream>>>(HENDB, AFULL);
  scan_ssd3<<<2048, 256, 0, stream>>>(BCBF, HENDB, DTA, Y);

  // --- gated RMSNorm ---
  norm_kernel<<<4096, 256, 0, stream>>>(Y, ZX, fnormw, bnormw, YN);

  // --- out-projections (both dirs fused) into concat buffer, then final Wo ---
  gemm_bt<1, 0><<<dim3(8, 16, 2), 256, 0, stream>>>(
      YN, WOUTT, (void*)OUT2, nullptr, 2048, 1024, 2048, 2048,
      (size_t)2048 * 2048, (size_t)1024 * 2048, (size_t)1024);
  gemm_bt<0, 1><<<dim3(8, 16), 256, 0, stream>>>(
      OUT2, WOT, d_out, bo, 2048, 1024, 2048, 1024, 0, 0, 0);
}